// Round 10
// baseline (366.269 us; speedup 1.0000x reference)
//
#include <hip/hip_runtime.h>
#include <hip/hip_bf16.h>
#include <type_traits>

// Problem constants (fixed by the reference)
#define DM   768
#define NH   12
#define HD   64
#define BATCH 8
#define SEQ  1024
#define NROWS (BATCH * SEQ)   // 8192

typedef short bf16x8 __attribute__((ext_vector_type(8)));
typedef float f32x4 __attribute__((ext_vector_type(4)));

// fp32 -> bf16 bits, round-half-up (2 VALU)
__device__ inline unsigned short f2b(float x) {
    union { float f; unsigned int u; } v; v.f = x;
    return (unsigned short)((v.u + 0x8000u) >> 16);
}
// pack two fp32 -> two bf16 (lo in low half): 2 v_add + 1 v_perm
__device__ inline unsigned int f2b2(float lo, float hi) {
    union { float f; unsigned int u; } a, b; a.f = lo; b.f = hi;
    return __builtin_amdgcn_perm(b.u + 0x8000u, a.u + 0x8000u, 0x07060302u);
}
// bf16 bits -> fp32
__device__ inline float b2f(unsigned short u) {
    union { float f; unsigned int x; } v; v.x = ((unsigned int)u) << 16;
    return v.f;
}

// async global->LDS, 16 B per lane; LDS dest = wave-uniform base + lane*16
__device__ inline void gld16(const unsigned short* g, unsigned short* l) {
    __builtin_amdgcn_global_load_lds(
        (const __attribute__((address_space(1))) unsigned int*)g,
        (__attribute__((address_space(3))) unsigned int*)l, 16, 0, 0);
}

// ---------------------------------------------------------------------------
// Kernel 0 (merged prep): z<6 -> weight convert+transpose; z==6 -> wod1 GEMM
// (x<12,y<12) and lens (y==12,x<16).   (round-9, passing)
// ---------------------------------------------------------------------------
__global__ __launch_bounds__(256) void prep_kernel(const float* __restrict__ w0,
                                                   const float* __restrict__ w1,
                                                   const float* __restrict__ w2,
                                                   const float* __restrict__ w3,
                                                   const float* __restrict__ w4,
                                                   const float* __restrict__ w5,
                                                   unsigned short* __restrict__ wt,
                                                   const int* __restrict__ m1,
                                                   const int* __restrict__ m2,
                                                   int* __restrict__ lens) {
    const int z = blockIdx.z;
    const int t = threadIdx.x;

    if (z < 6) {
        __shared__ float tile[32][33];
        const float* W = (z == 0) ? w0 : (z == 1) ? w1 : (z == 2) ? w2
                       : (z == 3) ? w3 : (z == 4) ? w4 : w5;
        unsigned short* Wt = wt + (size_t)z * DM * DM;
        const int n0 = blockIdx.x * 32;
        const int k0 = blockIdx.y * 32;
        const int tx = t & 31;
        const int ty = t >> 5;
#pragma unroll
        for (int r = 0; r < 4; ++r)
            tile[ty + 8 * r][tx] = W[(size_t)(k0 + ty + 8 * r) * DM + n0 + tx];
        __syncthreads();
#pragma unroll
        for (int r = 0; r < 4; ++r)
            Wt[(size_t)(n0 + ty + 8 * r) * DM + k0 + tx] = f2b(tile[tx][ty + 8 * r]);
        return;
    }

    if (blockIdx.y == 12) {
        if (blockIdx.x >= 16) return;
        __shared__ int redi[256];
        const int bid = blockIdx.x;
        const int b = bid & 7;
        const int* m = (bid < 8) ? m1 : m2;
        int cnt = 0;
        for (int i = t; i < SEQ; i += 256) cnt += (m[b * SEQ + i] != 0) ? 1 : 0;
        redi[t] = cnt;
        __syncthreads();
        for (int off = 128; off > 0; off >>= 1) {
            if (t < off) redi[t] += redi[t + off];
            __syncthreads();
        }
        if (t == 0) lens[bid] = redi[0];
        return;
    }

    if (blockIdx.x >= 12 || blockIdx.y >= 12) return;
    {
        __shared__ __align__(16) unsigned short As[64][40];
        __shared__ __align__(16) unsigned short Bs[64][40];
        unsigned short* out = wt + (size_t)6 * DM * DM;
        const float* Wo = w3;
        const float* d1w = w4;
        const int mb = blockIdx.x * 64;
        const int nb = blockIdx.y * 64;
        const int wid = t >> 6, lane = t & 63;
        const int quad = lane >> 4, l16 = lane & 15;
        const int bk = t >> 3, bn = (t & 7) * 8;
        const int am = t >> 2, ak = (t & 3) * 8;

        f32x4 acc[4];
#pragma unroll
        for (int c = 0; c < 4; ++c) acc[c] = (f32x4){0.f, 0.f, 0.f, 0.f};

        for (int j0 = 0; j0 < DM; j0 += 32) {
            {
                const float* s = &d1w[(size_t)(j0 + bk) * DM + mb + bn];
                float4 f0 = ((const float4*)s)[0];
                float4 f1 = ((const float4*)s)[1];
                As[bn + 0][bk] = f2b(f0.x); As[bn + 1][bk] = f2b(f0.y);
                As[bn + 2][bk] = f2b(f0.z); As[bn + 3][bk] = f2b(f0.w);
                As[bn + 4][bk] = f2b(f1.x); As[bn + 5][bk] = f2b(f1.y);
                As[bn + 6][bk] = f2b(f1.z); As[bn + 7][bk] = f2b(f1.w);
            }
            {
                const float* s = &Wo[(size_t)(nb + am) * DM + j0 + ak];
                float4 f0 = ((const float4*)s)[0];
                float4 f1 = ((const float4*)s)[1];
                uint4 p;
                p.x = f2b2(f0.x, f0.y); p.y = f2b2(f0.z, f0.w);
                p.z = f2b2(f1.x, f1.y); p.w = f2b2(f1.z, f1.w);
                *(uint4*)&Bs[am][ak] = p;
            }
            __syncthreads();
            bf16x8 av = *(const bf16x8*)&As[16 * wid + l16][quad * 8];
#pragma unroll
            for (int c = 0; c < 4; ++c) {
                bf16x8 bv = *(const bf16x8*)&Bs[16 * c + l16][quad * 8];
                acc[c] = __builtin_amdgcn_mfma_f32_16x16x32_bf16(av, bv, acc[c], 0, 0, 0);
            }
            __syncthreads();
        }
#pragma unroll
        for (int c = 0; c < 4; ++c) {
            const int col = nb + 16 * c + l16;
#pragma unroll
            for (int r = 0; r < 4; ++r) {
                const int row = mb + 16 * wid + quad * 4 + r;
                out[(size_t)row * DM + col] = f2b(acc[c][r]);
            }
        }
    }
}

// ---------------------------------------------------------------------------
// Kernel 0d: convert the three fp32 inputs to bf16 (round-9, passing).
// ---------------------------------------------------------------------------
__global__ __launch_bounds__(256) void cvt_in(const float* __restrict__ q,
                                              const float* __restrict__ k,
                                              const float* __restrict__ v,
                                              unsigned short* __restrict__ oq,
                                              unsigned short* __restrict__ ok,
                                              unsigned short* __restrict__ ov) {
    const int g = blockIdx.y;
    const float* src = (g == 0) ? q : (g == 1) ? k : v;
    unsigned short* dst = (g == 0) ? oq : (g == 1) ? ok : ov;
    const size_t i = ((size_t)blockIdx.x * 256 + threadIdx.x) * 8;
    float4 f0 = ((const float4*)(src + i))[0];
    float4 f1 = ((const float4*)(src + i))[1];
    uint4 p;
    p.x = f2b2(f0.x, f0.y); p.y = f2b2(f0.z, f0.w);
    p.z = f2b2(f1.x, f1.y); p.w = f2b2(f1.z, f1.w);
    *(uint4*)(dst + i) = p;
}

// ---------------------------------------------------------------------------
// Kernel 0e: transpose projected V (b2, [8192][768] bf16) into per-head
// vt_g[b][h][hd][seq] so attention can stage V with gld16 (no in-kernel
// transpose).  grid (16 seq-tiles, 96 bh), block 256.
// ---------------------------------------------------------------------------
__global__ __launch_bounds__(256) void vtr_kernel(const unsigned short* __restrict__ vin,
                                                  unsigned short* __restrict__ vt) {
    __shared__ unsigned short T[64][72];
    const int t = threadIdx.x;
    const int s0 = blockIdx.x * 64;
    const int bh = blockIdx.y;
    const int b = bh / NH, h = bh % NH;
    {   // read 64 seq rows x 64 hd cols, coalesced 32B per thread
        const int i = t >> 2, c = t & 3;
        const unsigned short* src = vin + (size_t)(b * SEQ + s0 + i) * DM + h * HD + c * 16;
        uint4 a0 = ((const uint4*)src)[0];
        uint4 a1 = ((const uint4*)src)[1];
        *(uint4*)&T[i][c * 16] = a0;
        *(uint4*)&T[i][c * 16 + 8] = a1;
    }
    __syncthreads();
    {   // write transposed: lane = hd (2-way LDS banks), 32B global chunks
        const int d = t & 63, c = t >> 6;
        union { uint4 u[2]; unsigned short s[16]; } pk;
#pragma unroll
        for (int j = 0; j < 16; ++j) pk.s[j] = T[c * 16 + j][d];
        unsigned short* dst = vt + (size_t)(bh * HD + d) * SEQ + s0 + c * 16;
        ((uint4*)dst)[0] = pk.u[0];
        ((uint4*)dst)[1] = pk.u[1];
    }
}

// ---------------------------------------------------------------------------
// Kernel 1a: grouped QKV GEMM — pure-bf16, gld16 both operands (round-9).
// Round-10: Q output (g==0) pre-scaled by 0.125*log2(e) so attention softmax
// is a bare exp2.
// ---------------------------------------------------------------------------
__global__ __launch_bounds__(256) void qkv_gemm(const unsigned short* __restrict__ aq,
                                                const unsigned short* __restrict__ akk,
                                                const unsigned short* __restrict__ av_,
                                                const unsigned short* __restrict__ wt,
                                                unsigned short* __restrict__ c0,
                                                unsigned short* __restrict__ c1,
                                                unsigned short* __restrict__ c2) {
    __shared__ __align__(16) unsigned short As[128][32];
    __shared__ __align__(16) unsigned short Ws[128][32];

    const int t = threadIdx.x;
    const int g = blockIdx.y / 6;
    const int m0 = blockIdx.x * 128;
    const int n0 = (blockIdx.y % 6) * 128;
    const unsigned short* A = (g == 0) ? aq : (g == 1) ? akk : av_;
    const unsigned short* Wt = wt + (size_t)g * DM * DM;
    unsigned short* C = (g == 0) ? c0 : (g == 1) ? c1 : c2;
    const float cs = (g == 0) ? 0.18033688f : 1.0f;   // 0.125*log2(e) for Q

    const int w = t >> 6, lane = t & 63;
    const int quad = lane >> 4, l16 = lane & 15;
    const int wm = w & 1, wn = w >> 1;
    const int srow = 16 * w + (lane >> 2);
    const int scol = 8 * (lane & 3);

    f32x4 acc[4][4];
#pragma unroll
    for (int i = 0; i < 4; ++i)
#pragma unroll
        for (int j = 0; j < 4; ++j) acc[i][j] = (f32x4){0.f, 0.f, 0.f, 0.f};

    for (int k0 = 0; k0 < DM; k0 += 32) {
#pragma unroll
        for (int j = 0; j < 2; ++j) {
            gld16(&A[(size_t)(m0 + srow + 64 * j) * DM + k0 + scol],
                  &As[16 * w + 64 * j][0]);
            gld16(&Wt[(size_t)(n0 + srow + 64 * j) * DM + k0 + scol],
                  &Ws[16 * w + 64 * j][0]);
        }
        __syncthreads();

        bf16x8 av[4], bv[4];
#pragma unroll
        for (int i = 0; i < 4; ++i)
            av[i] = *(const bf16x8*)&As[wm * 64 + 16 * i + l16][quad * 8];
#pragma unroll
        for (int i = 0; i < 4; ++i)
            bv[i] = *(const bf16x8*)&Ws[wn * 64 + 16 * i + l16][quad * 8];
#pragma unroll
        for (int i = 0; i < 4; ++i)
#pragma unroll
            for (int j = 0; j < 4; ++j)
                acc[i][j] = __builtin_amdgcn_mfma_f32_16x16x32_bf16(av[i], bv[j], acc[i][j], 0, 0, 0);
        __syncthreads();
    }

#pragma unroll
    for (int i = 0; i < 4; ++i)
#pragma unroll
        for (int j = 0; j < 4; ++j) {
            const int gn = n0 + wn * 64 + 16 * j + l16;
#pragma unroll
            for (int r = 0; r < 4; ++r) {
                const int gm = m0 + wm * 64 + 16 * i + quad * 4 + r;
                C[(size_t)gm * DM + gn] = f2b(acc[i][j][r] * cs);
            }
        }
}

// ---------------------------------------------------------------------------
// Kernel 1b: bf16 GEMM 128x128, gld16 both operands (round-9, passing).
// ---------------------------------------------------------------------------
template <typename CT>
__global__ __launch_bounds__(256) void gemm_bf(const unsigned short* __restrict__ A,
                                               const unsigned short* __restrict__ Wt,
                                               CT* __restrict__ C,
                                               const float* __restrict__ bias,
                                               const unsigned short* __restrict__ res,
                                               int relu) {
    __shared__ __align__(16) unsigned short As[128][32];
    __shared__ __align__(16) unsigned short Ws[128][32];

    const int t = threadIdx.x;
    const int m0 = blockIdx.x * 128;
    const int n0 = blockIdx.y * 128;
    const int w = t >> 6, lane = t & 63;
    const int quad = lane >> 4, l16 = lane & 15;
    const int wm = w & 1, wn = w >> 1;
    const int srow = 16 * w + (lane >> 2);
    const int scol = 8 * (lane & 3);

    f32x4 acc[4][4];
#pragma unroll
    for (int i = 0; i < 4; ++i)
#pragma unroll
        for (int j = 0; j < 4; ++j) acc[i][j] = (f32x4){0.f, 0.f, 0.f, 0.f};

    for (int k0 = 0; k0 < DM; k0 += 32) {
#pragma unroll
        for (int j = 0; j < 2; ++j) {
            gld16(&A[(size_t)(m0 + srow + 64 * j) * DM + k0 + scol],
                  &As[16 * w + 64 * j][0]);
            gld16(&Wt[(size_t)(n0 + srow + 64 * j) * DM + k0 + scol],
                  &Ws[16 * w + 64 * j][0]);
        }
        __syncthreads();

        bf16x8 av[4], bv[4];
#pragma unroll
        for (int i = 0; i < 4; ++i)
            av[i] = *(const bf16x8*)&As[wm * 64 + 16 * i + l16][quad * 8];
#pragma unroll
        for (int i = 0; i < 4; ++i)
            bv[i] = *(const bf16x8*)&Ws[wn * 64 + 16 * i + l16][quad * 8];
#pragma unroll
        for (int i = 0; i < 4; ++i)
#pragma unroll
            for (int j = 0; j < 4; ++j)
                acc[i][j] = __builtin_amdgcn_mfma_f32_16x16x32_bf16(av[i], bv[j], acc[i][j], 0, 0, 0);
        __syncthreads();
    }

#pragma unroll
    for (int i = 0; i < 4; ++i)
#pragma unroll
        for (int j = 0; j < 4; ++j) {
            const int gn = n0 + wn * 64 + 16 * j + l16;
            const float badd = bias ? bias[gn] : 0.0f;
#pragma unroll
            for (int r = 0; r < 4; ++r) {
                const int gm = m0 + wm * 64 + 16 * i + quad * 4 + r;
                float cv = acc[i][j][r] + badd;
                if (relu) cv = fmaxf(cv, 0.0f);
                if (res) cv += b2f(res[(size_t)gm * DM + gn]);
                if constexpr (std::is_same<CT, float>::value) {
                    C[(size_t)gm * DM + gn] = cv;
                } else {
                    C[(size_t)gm * DM + gn] = f2b(cv);
                }
            }
        }
}

// ---------------------------------------------------------------------------
// Kernel 1c: merged mha + ffn-hidden GEMM (round-9, passing).
// ---------------------------------------------------------------------------
__global__ __launch_bounds__(256) void gemm_mh(const unsigned short* __restrict__ A,
                                               const unsigned short* __restrict__ wt,
                                               unsigned short* __restrict__ cm,
                                               unsigned short* __restrict__ ch,
                                               const float* __restrict__ d1b) {
    __shared__ __align__(16) unsigned short As[128][32];
    __shared__ __align__(16) unsigned short Ws[128][32];

    const int t = threadIdx.x;
    const int unit = blockIdx.y / 6;
    const unsigned short* Wt = wt + (size_t)(unit ? 6 : 3) * DM * DM;
    unsigned short* C = unit ? ch : cm;
    const int m0 = blockIdx.x * 128;
    const int n0 = (blockIdx.y % 6) * 128;
    const int w = t >> 6, lane = t & 63;
    const int quad = lane >> 4, l16 = lane & 15;
    const int wm = w & 1, wn = w >> 1;
    const int srow = 16 * w + (lane >> 2);
    const int scol = 8 * (lane & 3);

    f32x4 acc[4][4];
#pragma unroll
    for (int i = 0; i < 4; ++i)
#pragma unroll
        for (int j = 0; j < 4; ++j) acc[i][j] = (f32x4){0.f, 0.f, 0.f, 0.f};

    for (int k0 = 0; k0 < DM; k0 += 32) {
#pragma unroll
        for (int j = 0; j < 2; ++j) {
            gld16(&A[(size_t)(m0 + srow + 64 * j) * DM + k0 + scol],
                  &As[16 * w + 64 * j][0]);
            gld16(&Wt[(size_t)(n0 + srow + 64 * j) * DM + k0 + scol],
                  &Ws[16 * w + 64 * j][0]);
        }
        __syncthreads();

        bf16x8 av[4], bv[4];
#pragma unroll
        for (int i = 0; i < 4; ++i)
            av[i] = *(const bf16x8*)&As[wm * 64 + 16 * i + l16][quad * 8];
#pragma unroll
        for (int i = 0; i < 4; ++i)
            bv[i] = *(const bf16x8*)&Ws[wn * 64 + 16 * i + l16][quad * 8];
#pragma unroll
        for (int i = 0; i < 4; ++i)
#pragma unroll
            for (int j = 0; j < 4; ++j)
                acc[i][j] = __builtin_amdgcn_mfma_f32_16x16x32_bf16(av[i], bv[j], acc[i][j], 0, 0, 0);
        __syncthreads();
    }

#pragma unroll
    for (int i = 0; i < 4; ++i)
#pragma unroll
        for (int j = 0; j < 4; ++j) {
            const int gn = n0 + wn * 64 + 16 * j + l16;
            const float badd = unit ? d1b[gn] : 0.0f;
#pragma unroll
            for (int r = 0; r < 4; ++r) {
                const int gm = m0 + wm * 64 + 16 * i + quad * 4 + r;
                float cv = acc[i][j][r] + badd;
                if (unit) cv = fmaxf(cv, 0.0f);
                C[(size_t)gm * DM + gn] = f2b(cv);
            }
        }
}

// ---------------------------------------------------------------------------
// Kernel 2: MFMA flash attention, round-10 rework.
//  - K and V (pre-transposed vt_g) staged via gld16, double-buffered, ONE
//    barrier per tile (prefetch issued right after barrier -> ages a full
//    compute phase before the next barrier's vmcnt drain).
//  - gld16 can't pad, so the GLOBAL 16B group per lane is XOR-swizzled:
//    lane fetches group (lane&7)^(lane>>3); fragment reads unswizzle with
//    slot = group ^ (row&7) -> 2-way LDS bank access (free).
//  - Softmax: Q pre-scaled by 0.125*log2(e) in qkv epilogue -> p = exp2(s).
// O written in place over Q (regions disjoint per block; Q read at start).
// ---------------------------------------------------------------------------
__global__ __launch_bounds__(256) void attn_mfma(const unsigned short* Q,
                                                 const unsigned short* __restrict__ K,
                                                 const unsigned short* __restrict__ Vt,
                                                 unsigned short* O,
                                                 const int* __restrict__ lens) {
    __shared__ __align__(16) unsigned short Ks[2][64][64];   // [key][hd] swizzled
    __shared__ __align__(16) unsigned short Vs[2][64][64];   // [hd][key] swizzled
    __shared__ __align__(16) unsigned short Ps[4][16][72];   // per-wave P, swizzled

    const int t = threadIdx.x;
    const int bid = blockIdx.x;
    const int q0 = (bid & 15) * 64;
    const int h = (bid >> 4) % NH;
    const int b = bid / (16 * NH);
    const int vl1 = lens[b];
    const int vl2 = lens[8 + b];
    const int wid = t >> 6;
    const int lane = t & 63;
    const int quad = lane >> 4;
    const int l16 = lane & 15;

    // Q fragments (A-operand), pre-scaled by 0.125*log2(e)
    bf16x8 qa0, qa1;
    {
        const unsigned short* qp =
            &Q[(size_t)(b * SEQ + q0 + 16 * wid + l16) * DM + h * HD + quad * 8];
        qa0 = *(const bf16x8*)qp;
        qa1 = *(const bf16x8*)(qp + 32);
    }

    f32x4 o[4];
#pragma unroll
    for (int ct = 0; ct < 4; ++ct) o[ct] = (f32x4){0.f, 0.f, 0.f, 0.f};
    float suml[4];
    bool rbad[4];
#pragma unroll
    for (int r = 0; r < 4; ++r) {
        suml[r] = 0.0f;
        rbad[r] = ((q0 + 16 * wid + quad * 4 + r) >= vl2) || (vl1 == 0);
    }

    // gld16 staging constants: lane covers row ri=lane>>3 (of 8/instr),
    // swizzled 16B group (lane&7)^ri
    const int ri = lane >> 3;
    const int gsw = ((lane & 7) ^ ri) * 8;            // shorts
    const unsigned short* kb = K + (size_t)(b * SEQ) * DM + h * HD + gsw;
    const unsigned short* vb = Vt + ((size_t)(b * NH + h) * HD) * SEQ + gsw;

    // prologue: stage tile 0 into buffer 0
#pragma unroll
    for (int j = 0; j < 2; ++j) {
        const int rr = 16 * wid + 8 * j + ri;
        gld16(&kb[(size_t)rr * DM], &Ks[0][16 * wid + 8 * j][0]);
        gld16(&vb[(size_t)rr * SEQ], &Vs[0][16 * wid + 8 * j][0]);
    }

    // Ps swizzle read keys
    const int k2 = l16 >> 2;
    // fragment unswizzle slots (depend on row&7 = l16&7)
    const int sw0 = (quad ^ (l16 & 7)) * 8;
    const int sw1 = ((4 + quad) ^ (l16 & 7)) * 8;

    for (int tile = 0; tile < 16; ++tile) {
        const int buf = tile & 1;
        const int c0 = tile * 64;
        __syncthreads();   // drains prefetch gld16 -> buf ready; prev reads done

        if (tile < 15) {   // prefetch next tile into buf^1 (async)
#pragma unroll
            for (int j = 0; j < 2; ++j) {
                const int rr = 16 * wid + 8 * j + ri;
                gld16(&kb[(size_t)(c0 + 64 + rr) * DM], &Ks[buf ^ 1][16 * wid + 8 * j][0]);
                gld16(&vb[(size_t)rr * SEQ + c0 + 64], &Vs[buf ^ 1][16 * wid + 8 * j][0]);
            }
        }

        // S = Q K^T
        f32x4 s[4];
#pragma unroll
        for (int ct = 0; ct < 4; ++ct) {
            f32x4 acc = (f32x4){0.f, 0.f, 0.f, 0.f};
            bf16x8 b0v = *(const bf16x8*)&Ks[buf][16 * ct + l16][sw0];
            bf16x8 b1v = *(const bf16x8*)&Ks[buf][16 * ct + l16][sw1];
            acc = __builtin_amdgcn_mfma_f32_16x16x32_bf16(qa0, b0v, acc, 0, 0, 0);
            acc = __builtin_amdgcn_mfma_f32_16x16x32_bf16(qa1, b1v, acc, 0, 0, 0);
            s[ct] = acc;
        }
        // p = exp2(s) with masking (Q carries the scale)
#pragma unroll
        for (int ct = 0; ct < 4; ++ct) {
            const bool kok = (c0 + 16 * ct + l16) < vl1;
#pragma unroll
            for (int r = 0; r < 4; ++r) {
                float e = exp2f(s[ct][r]);
                float p = kok ? e : 0.0f;
                p = rbad[r] ? 1.0f : p;
                s[ct][r] = p;
                suml[r] += p;
            }
        }
        // P -> per-wave LDS (C layout -> A layout), XOR-swizzled 16B groups
#pragma unroll
        for (int ct = 0; ct < 4; ++ct) {
            const int gidx = 2 * ct + (l16 >> 3);
            const int c = l16 & 7;
            const int gs = (gidx ^ quad) * 8 + c;
#pragma unroll
            for (int r = 0; r < 4; ++r)
                Ps[wid][quad * 4 + r][gs] = f2b(s[ct][r]);
        }
        bf16x8 pa0 = *(const bf16x8*)&Ps[wid][l16][(quad ^ k2) * 8];
        bf16x8 pa1 = *(const bf16x8*)&Ps[wid][l16][((4 + quad) ^ k2) * 8];
        // O += P V
#pragma unroll
        for (int ct = 0; ct < 4; ++ct) {
            bf16x8 vb0 = *(const bf16x8*)&Vs[buf][16 * ct + l16][sw0];
            bf16x8 vb1 = *(const bf16x8*)&Vs[buf][16 * ct + l16][sw1];
            o[ct] = __builtin_amdgcn_mfma_f32_16x16x32_bf16(pa0, vb0, o[ct], 0, 0, 0);
            o[ct] = __builtin_amdgcn_mfma_f32_16x16x32_bf16(pa1, vb1, o[ct], 0, 0, 0);
        }
    }

    // epilogue: reduce l across the 16 lanes of each row group, O /= l
#pragma unroll
    for (int d = 1; d < 16; d <<= 1) {
#pragma unroll
        for (int r = 0; r < 4; ++r) suml[r] += __shfl_xor(suml[r], d, 64);
    }
#pragma unroll
    for (int r = 0; r < 4; ++r) {
        float inv = 1.0f / suml[r];
        const size_t row = (size_t)(b * SEQ + q0 + 16 * wid + quad * 4 + r);
#pragma unroll
        for (int ct = 0; ct < 4; ++ct) {
            O[row * DM + h * HD + 16 * ct + l16] = f2b(o[ct][r] * inv);
        }
    }
}

// ---------------------------------------------------------------------------
// Kernel 3: row LayerNorm over D=768, fp32 in/out, IN PLACE on d_out.
// ---------------------------------------------------------------------------
__global__ __launch_bounds__(256) void ln_kernel(float* __restrict__ X,
                                                 const float* __restrict__ g,
                                                 const float* __restrict__ bvec) {
    __shared__ float red[256];
    const int row = blockIdx.x;
    const int t = threadIdx.x;
    float* xr = X + (size_t)row * DM;
    float x0 = xr[t];
    float x1 = xr[t + 256];
    float x2 = xr[t + 512];
    red[t] = x0 + x1 + x2;
    __syncthreads();
    for (int off = 128; off > 0; off >>= 1) {
        if (t < off) red[t] += red[t + off];
        __syncthreads();
    }
    float mu = red[0] * (1.0f / 768.0f);
    __syncthreads();
    float d0 = x0 - mu, d1 = x1 - mu, d2 = x2 - mu;
    red[t] = d0 * d0 + d1 * d1 + d2 * d2;
    __syncthreads();
    for (int off = 128; off > 0; off >>= 1) {
        if (t < off) red[t] += red[t + off];
        __syncthreads();
    }
    float rstd = rsqrtf(red[0] * (1.0f / 768.0f) + 1e-5f);
    xr[t]       = d0 * rstd * g[t]       + bvec[t];
    xr[t + 256] = d1 * rstd * g[t + 256] + bvec[t + 256];
    xr[t + 512] = d2 * rstd * g[t + 512] + bvec[t + 512];
}

// ---------------------------------------------------------------------------
extern "C" void kernel_launch(void* const* d_in, const int* in_sizes, int n_in,
                              void* d_out, int out_size, void* d_ws, size_t ws_size,
                              hipStream_t stream) {
    const float* queries = (const float*)d_in[0];
    const float* keys    = (const float*)d_in[1];
    const float* values  = (const float*)d_in[2];
    const int* mask1 = (const int*)d_in[3];
    const int* mask2 = (const int*)d_in[4];
    const float* Wq  = (const float*)d_in[5];
    const float* Wk  = (const float*)d_in[6];
    const float* Wv  = (const float*)d_in[7];
    const float* Wo  = (const float*)d_in[8];
    const float* d1w = (const float*)d_in[9];
    const float* d1b = (const float*)d_in[10];
    const float* d2w = (const float*)d_in[11];
    const float* d2b = (const float*)d_in[12];
    const float* lng = (const float*)d_in[13];
    const float* lnb = (const float*)d_in[14];

    // workspace: [lens 256B][b0][b1][b2][Wt x7][aq][ak][av][vt_g]  (~97 MB)
    char* ws = (char*)d_ws;
    int* lens = (int*)ws;
    const size_t NB = (size_t)NROWS * DM * sizeof(unsigned short);   // 12.58 MB
    const size_t WT = (size_t)DM * DM;
    unsigned short* b0 = (unsigned short*)(ws + 256);
    unsigned short* b1 = (unsigned short*)(ws + 256 + NB);
    unsigned short* b2 = (unsigned short*)(ws + 256 + 2 * NB);
    unsigned short* wt = (unsigned short*)(ws + 256 + 3 * NB);       // 7 x 768*768
    unsigned short* aq = (unsigned short*)(ws + 256 + 3 * NB + 7 * WT * sizeof(unsigned short));
    unsigned short* ak = aq + (size_t)NROWS * DM;
    unsigned short* av = ak + (size_t)NROWS * DM;
    unsigned short* vtg = av + (size_t)NROWS * DM;                   // [96][64][1024]
    float* xout = (float*)d_out;

    // prep: weight cvt (z<6), wod1 + lens (z==6)
    prep_kernel<<<dim3(24, 24, 7), 256, 0, stream>>>(Wq, Wk, Wv, Wo, d1w, d2w,
                                                     wt, mask1, mask2, lens);
    // convert fp32 inputs -> bf16
    cvt_in<<<dim3(NROWS * DM / 8 / 256, 3), 256, 0, stream>>>(queries, keys, values,
                                                              aq, ak, av);

    // grouped QKV projection (Q output pre-scaled for exp2 softmax)
    qkv_gemm<<<dim3(64, 18), 256, 0, stream>>>(aq, ak, av, wt, b0, b1, b2);

    // transpose projected V into per-head [hd][seq] for gld16 staging
    vtr_kernel<<<dim3(16, 96), 256, 0, stream>>>(b2, vtg);

    attn_mfma<<<16 * NH * BATCH, 256, 0, stream>>>(b0, b1, vtg, b0, lens);  // O over Q

    // merged: mha -> b1, h = relu(attnout@Wod1 + d1b) -> b2
    gemm_mh<<<dim3(64, 12), 256, 0, stream>>>(b0, wt, b1, b2, d1b);

    // x = h @ d2w + d2b + mha -> d_out (fp32)
    gemm_bf<float><<<dim3(64, 6), 256, 0, stream>>>(b2, wt + 5 * WT, xout, d2b, b1, 0);

    ln_kernel<<<NROWS, 256, 0, stream>>>(xout, lng, lnb);  // in place
}

// Round 11
// 335.436 us; speedup vs baseline: 1.0919x; 1.0919x over previous
//
#include <hip/hip_runtime.h>
#include <hip/hip_bf16.h>
#include <type_traits>

// Problem constants (fixed by the reference)
#define DM   768
#define NH   12
#define HD   64
#define BATCH 8
#define SEQ  1024
#define NROWS (BATCH * SEQ)   // 8192

typedef short bf16x8 __attribute__((ext_vector_type(8)));
typedef float f32x4 __attribute__((ext_vector_type(4)));

// fp32 -> bf16 bits, round-half-up (2 VALU)
__device__ inline unsigned short f2b(float x) {
    union { float f; unsigned int u; } v; v.f = x;
    return (unsigned short)((v.u + 0x8000u) >> 16);
}
// pack two fp32 -> two bf16 (lo in low half): 2 v_add + 1 v_perm
__device__ inline unsigned int f2b2(float lo, float hi) {
    union { float f; unsigned int u; } a, b; a.f = lo; b.f = hi;
    return __builtin_amdgcn_perm(b.u + 0x8000u, a.u + 0x8000u, 0x07060302u);
}
// bf16 bits -> fp32
__device__ inline float b2f(unsigned short u) {
    union { float f; unsigned int x; } v; v.x = ((unsigned int)u) << 16;
    return v.f;
}

// async global->LDS, 16 B per lane; LDS dest = wave-uniform base + lane*16
__device__ inline void gld16(const unsigned short* g, unsigned short* l) {
    __builtin_amdgcn_global_load_lds(
        (const __attribute__((address_space(1))) unsigned int*)g,
        (__attribute__((address_space(3))) unsigned int*)l, 16, 0, 0);
}

// ---------------------------------------------------------------------------
// Kernel 0 (merged prep): z<6 -> weight convert+transpose; z==6 -> wod1 GEMM
// (x<12,y<12) + lens (y==12,x<16); z>=7 -> input fp32->bf16 convert planes
// (fills the machine while z==6's serial tail runs).
// ---------------------------------------------------------------------------
__global__ __launch_bounds__(256) void prep_kernel(const float* __restrict__ w0,
                                                   const float* __restrict__ w1,
                                                   const float* __restrict__ w2,
                                                   const float* __restrict__ w3,
                                                   const float* __restrict__ w4,
                                                   const float* __restrict__ w5,
                                                   unsigned short* __restrict__ wt,
                                                   const int* __restrict__ m1,
                                                   const int* __restrict__ m2,
                                                   int* __restrict__ lens,
                                                   const float* __restrict__ qin,
                                                   const float* __restrict__ kin,
                                                   const float* __restrict__ vin,
                                                   unsigned short* __restrict__ oq,
                                                   unsigned short* __restrict__ ok,
                                                   unsigned short* __restrict__ ov) {
    const int z = blockIdx.z;
    const int t = threadIdx.x;

    if (z >= 7) {
        // ---- input convert: 16 planes x 576 blocks = 9216 = 3 x 3072 ----
        const int linear = (z - 7) * 576 + blockIdx.y * 24 + blockIdx.x;
        const int g = linear / 3072;
        const int r = linear % 3072;
        const float* src = (g == 0) ? qin : (g == 1) ? kin : vin;
        unsigned short* dst = (g == 0) ? oq : (g == 1) ? ok : ov;
        const size_t i = ((size_t)r * 256 + t) * 8;
        float4 f0 = ((const float4*)(src + i))[0];
        float4 f1 = ((const float4*)(src + i))[1];
        uint4 p;
        p.x = f2b2(f0.x, f0.y); p.y = f2b2(f0.z, f0.w);
        p.z = f2b2(f1.x, f1.y); p.w = f2b2(f1.z, f1.w);
        *(uint4*)(dst + i) = p;
        return;
    }

    if (z < 6) {
        __shared__ float tile[32][33];
        const float* W = (z == 0) ? w0 : (z == 1) ? w1 : (z == 2) ? w2
                       : (z == 3) ? w3 : (z == 4) ? w4 : w5;
        unsigned short* Wt = wt + (size_t)z * DM * DM;
        const int n0 = blockIdx.x * 32;
        const int k0 = blockIdx.y * 32;
        const int tx = t & 31;
        const int ty = t >> 5;
#pragma unroll
        for (int r = 0; r < 4; ++r)
            tile[ty + 8 * r][tx] = W[(size_t)(k0 + ty + 8 * r) * DM + n0 + tx];
        __syncthreads();
#pragma unroll
        for (int r = 0; r < 4; ++r)
            Wt[(size_t)(n0 + ty + 8 * r) * DM + k0 + tx] = f2b(tile[tx][ty + 8 * r]);
        return;
    }

    if (blockIdx.y == 12) {
        if (blockIdx.x >= 16) return;
        __shared__ int redi[256];
        const int bid = blockIdx.x;
        const int b = bid & 7;
        const int* m = (bid < 8) ? m1 : m2;
        int cnt = 0;
        for (int i = t; i < SEQ; i += 256) cnt += (m[b * SEQ + i] != 0) ? 1 : 0;
        redi[t] = cnt;
        __syncthreads();
        for (int off = 128; off > 0; off >>= 1) {
            if (t < off) redi[t] += redi[t + off];
            __syncthreads();
        }
        if (t == 0) lens[bid] = redi[0];
        return;
    }

    if (blockIdx.x >= 12 || blockIdx.y >= 12) return;
    {
        __shared__ __align__(16) unsigned short As[64][40];
        __shared__ __align__(16) unsigned short Bs[64][40];
        unsigned short* out = wt + (size_t)6 * DM * DM;
        const float* Wo = w3;
        const float* d1w = w4;
        const int mb = blockIdx.x * 64;
        const int nb = blockIdx.y * 64;
        const int wid = t >> 6, lane = t & 63;
        const int quad = lane >> 4, l16 = lane & 15;
        const int bk = t >> 3, bn = (t & 7) * 8;
        const int am = t >> 2, ak = (t & 3) * 8;

        f32x4 acc[4];
#pragma unroll
        for (int c = 0; c < 4; ++c) acc[c] = (f32x4){0.f, 0.f, 0.f, 0.f};

        for (int j0 = 0; j0 < DM; j0 += 32) {
            {
                const float* s = &d1w[(size_t)(j0 + bk) * DM + mb + bn];
                float4 f0 = ((const float4*)s)[0];
                float4 f1 = ((const float4*)s)[1];
                As[bn + 0][bk] = f2b(f0.x); As[bn + 1][bk] = f2b(f0.y);
                As[bn + 2][bk] = f2b(f0.z); As[bn + 3][bk] = f2b(f0.w);
                As[bn + 4][bk] = f2b(f1.x); As[bn + 5][bk] = f2b(f1.y);
                As[bn + 6][bk] = f2b(f1.z); As[bn + 7][bk] = f2b(f1.w);
            }
            {
                const float* s = &Wo[(size_t)(nb + am) * DM + j0 + ak];
                float4 f0 = ((const float4*)s)[0];
                float4 f1 = ((const float4*)s)[1];
                uint4 p;
                p.x = f2b2(f0.x, f0.y); p.y = f2b2(f0.z, f0.w);
                p.z = f2b2(f1.x, f1.y); p.w = f2b2(f1.z, f1.w);
                *(uint4*)&Bs[am][ak] = p;
            }
            __syncthreads();
            bf16x8 av = *(const bf16x8*)&As[16 * wid + l16][quad * 8];
#pragma unroll
            for (int c = 0; c < 4; ++c) {
                bf16x8 bv = *(const bf16x8*)&Bs[16 * c + l16][quad * 8];
                acc[c] = __builtin_amdgcn_mfma_f32_16x16x32_bf16(av, bv, acc[c], 0, 0, 0);
            }
            __syncthreads();
        }
#pragma unroll
        for (int c = 0; c < 4; ++c) {
            const int col = nb + 16 * c + l16;
#pragma unroll
            for (int r = 0; r < 4; ++r) {
                const int row = mb + 16 * wid + quad * 4 + r;
                out[(size_t)row * DM + col] = f2b(acc[c][r]);
            }
        }
    }
}

// ---------------------------------------------------------------------------
// Kernel 1a: grouped QKV GEMM — pure-bf16, gld16 both operands (round-9,
// passing). Q output pre-scaled by 0.125*log2(e) so attention softmax is a
// bare exp2 (numerics validated round 10).
// ---------------------------------------------------------------------------
__global__ __launch_bounds__(256) void qkv_gemm(const unsigned short* __restrict__ aq,
                                                const unsigned short* __restrict__ akk,
                                                const unsigned short* __restrict__ av_,
                                                const unsigned short* __restrict__ wt,
                                                unsigned short* __restrict__ c0,
                                                unsigned short* __restrict__ c1,
                                                unsigned short* __restrict__ c2) {
    __shared__ __align__(16) unsigned short As[128][32];
    __shared__ __align__(16) unsigned short Ws[128][32];

    const int t = threadIdx.x;
    const int g = blockIdx.y / 6;
    const int m0 = blockIdx.x * 128;
    const int n0 = (blockIdx.y % 6) * 128;
    const unsigned short* A = (g == 0) ? aq : (g == 1) ? akk : av_;
    const unsigned short* Wt = wt + (size_t)g * DM * DM;
    unsigned short* C = (g == 0) ? c0 : (g == 1) ? c1 : c2;
    const float cs = (g == 0) ? 0.18033688f : 1.0f;   // 0.125*log2(e) for Q

    const int w = t >> 6, lane = t & 63;
    const int quad = lane >> 4, l16 = lane & 15;
    const int wm = w & 1, wn = w >> 1;
    const int srow = 16 * w + (lane >> 2);
    const int scol = 8 * (lane & 3);

    f32x4 acc[4][4];
#pragma unroll
    for (int i = 0; i < 4; ++i)
#pragma unroll
        for (int j = 0; j < 4; ++j) acc[i][j] = (f32x4){0.f, 0.f, 0.f, 0.f};

    for (int k0 = 0; k0 < DM; k0 += 32) {
#pragma unroll
        for (int j = 0; j < 2; ++j) {
            gld16(&A[(size_t)(m0 + srow + 64 * j) * DM + k0 + scol],
                  &As[16 * w + 64 * j][0]);
            gld16(&Wt[(size_t)(n0 + srow + 64 * j) * DM + k0 + scol],
                  &Ws[16 * w + 64 * j][0]);
        }
        __syncthreads();

        bf16x8 av[4], bv[4];
#pragma unroll
        for (int i = 0; i < 4; ++i)
            av[i] = *(const bf16x8*)&As[wm * 64 + 16 * i + l16][quad * 8];
#pragma unroll
        for (int i = 0; i < 4; ++i)
            bv[i] = *(const bf16x8*)&Ws[wn * 64 + 16 * i + l16][quad * 8];
#pragma unroll
        for (int i = 0; i < 4; ++i)
#pragma unroll
            for (int j = 0; j < 4; ++j)
                acc[i][j] = __builtin_amdgcn_mfma_f32_16x16x32_bf16(av[i], bv[j], acc[i][j], 0, 0, 0);
        __syncthreads();
    }

#pragma unroll
    for (int i = 0; i < 4; ++i)
#pragma unroll
        for (int j = 0; j < 4; ++j) {
            const int gn = n0 + wn * 64 + 16 * j + l16;
#pragma unroll
            for (int r = 0; r < 4; ++r) {
                const int gm = m0 + wm * 64 + 16 * i + quad * 4 + r;
                C[(size_t)gm * DM + gn] = f2b(acc[i][j][r] * cs);
            }
        }
}

// ---------------------------------------------------------------------------
// Kernel 1b: bf16 GEMM 128x128, gld16 both operands (round-9, passing).
// ---------------------------------------------------------------------------
template <typename CT>
__global__ __launch_bounds__(256) void gemm_bf(const unsigned short* __restrict__ A,
                                               const unsigned short* __restrict__ Wt,
                                               CT* __restrict__ C,
                                               const float* __restrict__ bias,
                                               const unsigned short* __restrict__ res,
                                               int relu) {
    __shared__ __align__(16) unsigned short As[128][32];
    __shared__ __align__(16) unsigned short Ws[128][32];

    const int t = threadIdx.x;
    const int m0 = blockIdx.x * 128;
    const int n0 = blockIdx.y * 128;
    const int w = t >> 6, lane = t & 63;
    const int quad = lane >> 4, l16 = lane & 15;
    const int wm = w & 1, wn = w >> 1;
    const int srow = 16 * w + (lane >> 2);
    const int scol = 8 * (lane & 3);

    f32x4 acc[4][4];
#pragma unroll
    for (int i = 0; i < 4; ++i)
#pragma unroll
        for (int j = 0; j < 4; ++j) acc[i][j] = (f32x4){0.f, 0.f, 0.f, 0.f};

    for (int k0 = 0; k0 < DM; k0 += 32) {
#pragma unroll
        for (int j = 0; j < 2; ++j) {
            gld16(&A[(size_t)(m0 + srow + 64 * j) * DM + k0 + scol],
                  &As[16 * w + 64 * j][0]);
            gld16(&Wt[(size_t)(n0 + srow + 64 * j) * DM + k0 + scol],
                  &Ws[16 * w + 64 * j][0]);
        }
        __syncthreads();

        bf16x8 av[4], bv[4];
#pragma unroll
        for (int i = 0; i < 4; ++i)
            av[i] = *(const bf16x8*)&As[wm * 64 + 16 * i + l16][quad * 8];
#pragma unroll
        for (int i = 0; i < 4; ++i)
            bv[i] = *(const bf16x8*)&Ws[wn * 64 + 16 * i + l16][quad * 8];
#pragma unroll
        for (int i = 0; i < 4; ++i)
#pragma unroll
            for (int j = 0; j < 4; ++j)
                acc[i][j] = __builtin_amdgcn_mfma_f32_16x16x32_bf16(av[i], bv[j], acc[i][j], 0, 0, 0);
        __syncthreads();
    }

#pragma unroll
    for (int i = 0; i < 4; ++i)
#pragma unroll
        for (int j = 0; j < 4; ++j) {
            const int gn = n0 + wn * 64 + 16 * j + l16;
            const float badd = bias ? bias[gn] : 0.0f;
#pragma unroll
            for (int r = 0; r < 4; ++r) {
                const int gm = m0 + wm * 64 + 16 * i + quad * 4 + r;
                float cv = acc[i][j][r] + badd;
                if (relu) cv = fmaxf(cv, 0.0f);
                if (res) cv += b2f(res[(size_t)gm * DM + gn]);
                if constexpr (std::is_same<CT, float>::value) {
                    C[(size_t)gm * DM + gn] = cv;
                } else {
                    C[(size_t)gm * DM + gn] = f2b(cv);
                }
            }
        }
}

// ---------------------------------------------------------------------------
// Kernel 1c: merged mha + ffn-hidden GEMM (round-9, passing).
// ---------------------------------------------------------------------------
__global__ __launch_bounds__(256) void gemm_mh(const unsigned short* __restrict__ A,
                                               const unsigned short* __restrict__ wt,
                                               unsigned short* __restrict__ cm,
                                               unsigned short* __restrict__ ch,
                                               const float* __restrict__ d1b) {
    __shared__ __align__(16) unsigned short As[128][32];
    __shared__ __align__(16) unsigned short Ws[128][32];

    const int t = threadIdx.x;
    const int unit = blockIdx.y / 6;
    const unsigned short* Wt = wt + (size_t)(unit ? 6 : 3) * DM * DM;
    unsigned short* C = unit ? ch : cm;
    const int m0 = blockIdx.x * 128;
    const int n0 = (blockIdx.y % 6) * 128;
    const int w = t >> 6, lane = t & 63;
    const int quad = lane >> 4, l16 = lane & 15;
    const int wm = w & 1, wn = w >> 1;
    const int srow = 16 * w + (lane >> 2);
    const int scol = 8 * (lane & 3);

    f32x4 acc[4][4];
#pragma unroll
    for (int i = 0; i < 4; ++i)
#pragma unroll
        for (int j = 0; j < 4; ++j) acc[i][j] = (f32x4){0.f, 0.f, 0.f, 0.f};

    for (int k0 = 0; k0 < DM; k0 += 32) {
#pragma unroll
        for (int j = 0; j < 2; ++j) {
            gld16(&A[(size_t)(m0 + srow + 64 * j) * DM + k0 + scol],
                  &As[16 * w + 64 * j][0]);
            gld16(&Wt[(size_t)(n0 + srow + 64 * j) * DM + k0 + scol],
                  &Ws[16 * w + 64 * j][0]);
        }
        __syncthreads();

        bf16x8 av[4], bv[4];
#pragma unroll
        for (int i = 0; i < 4; ++i)
            av[i] = *(const bf16x8*)&As[wm * 64 + 16 * i + l16][quad * 8];
#pragma unroll
        for (int i = 0; i < 4; ++i)
            bv[i] = *(const bf16x8*)&Ws[wn * 64 + 16 * i + l16][quad * 8];
#pragma unroll
        for (int i = 0; i < 4; ++i)
#pragma unroll
            for (int j = 0; j < 4; ++j)
                acc[i][j] = __builtin_amdgcn_mfma_f32_16x16x32_bf16(av[i], bv[j], acc[i][j], 0, 0, 0);
        __syncthreads();
    }

#pragma unroll
    for (int i = 0; i < 4; ++i)
#pragma unroll
        for (int j = 0; j < 4; ++j) {
            const int gn = n0 + wn * 64 + 16 * j + l16;
            const float badd = unit ? d1b[gn] : 0.0f;
#pragma unroll
            for (int r = 0; r < 4; ++r) {
                const int gm = m0 + wm * 64 + 16 * i + quad * 4 + r;
                float cv = acc[i][j][r] + badd;
                if (unit) cv = fmaxf(cv, 0.0f);
                C[(size_t)gm * DM + gn] = f2b(cv);
            }
        }
}

// ---------------------------------------------------------------------------
// Kernel 2: MFMA flash attention — EXACT round-9 structure (fastest measured:
// 68 µs; round-10's dbuf/swizzle variant regressed via occupancy loss).
// Only change: softmax is exp2f (Q pre-scaled by 0.125*log2e in qkv).
// ---------------------------------------------------------------------------
__global__ __launch_bounds__(256) void attn_mfma(const unsigned short* Q,
                                                 const unsigned short* __restrict__ K,
                                                 const unsigned short* __restrict__ V,
                                                 unsigned short* O,
                                                 const int* __restrict__ lens) {
    __shared__ __align__(16) unsigned short Ks[64][72];
    __shared__ __align__(16) unsigned short Vt[64][72];
    __shared__ __align__(16) unsigned short Ps[4][16][72];

    const int t = threadIdx.x;
    const int bid = blockIdx.x;
    const int q0 = (bid & 15) * 64;
    const int h = (bid >> 4) % NH;
    const int b = bid / (16 * NH);
    const int vl1 = lens[b];
    const int vl2 = lens[8 + b];
    const int wid = t >> 6;
    const int lane = t & 63;
    const int quad = lane >> 4;
    const int l16 = lane & 15;

    bf16x8 qa0, qa1;
    {
        const unsigned short* qp =
            &Q[(size_t)(b * SEQ + q0 + 16 * wid + l16) * DM + h * HD + quad * 8];
        qa0 = *(const bf16x8*)qp;
        qa1 = *(const bf16x8*)(qp + 32);
    }

    f32x4 o[4];
#pragma unroll
    for (int ct = 0; ct < 4; ++ct) o[ct] = (f32x4){0.f, 0.f, 0.f, 0.f};
    float suml[4];
    bool rbad[4];
#pragma unroll
    for (int r = 0; r < 4; ++r) {
        suml[r] = 0.0f;
        rbad[r] = ((q0 + 16 * wid + quad * 4 + r) >= vl2) || (vl1 == 0);
    }

    const int kkr = t >> 3;
    const int khc = (t & 7) * 8;
    const unsigned short* kbase = &K[(size_t)(b * SEQ) * DM + h * HD];
    const unsigned short* vbase = &V[(size_t)(b * SEQ) * DM + h * HD];

    uint4 kr0 = *(const uint4*)&kbase[(size_t)kkr * DM + khc];
    uint4 kr1 = *(const uint4*)&kbase[(size_t)(kkr + 32) * DM + khc];
    uint4 vr0 = *(const uint4*)&vbase[(size_t)lane * DM + wid * 16];
    uint4 vr1 = *(const uint4*)&vbase[(size_t)lane * DM + wid * 16 + 8];

    const int k2 = l16 >> 2;

    for (int tile = 0; tile < 16; ++tile) {
        const int c0 = tile * 64;
        *(uint4*)&Ks[kkr][khc] = kr0;
        *(uint4*)&Ks[kkr + 32][khc] = kr1;
        {
            union { uint4 u; unsigned short s[8]; } va, vb;
            va.u = vr0; vb.u = vr1;
#pragma unroll
            for (int j = 0; j < 8; ++j) Vt[wid * 16 + j][lane] = va.s[j];
#pragma unroll
            for (int j = 0; j < 8; ++j) Vt[wid * 16 + 8 + j][lane] = vb.s[j];
        }
        __syncthreads();

        if (tile < 15) {
            const int c1 = c0 + 64;
            kr0 = *(const uint4*)&kbase[(size_t)(c1 + kkr) * DM + khc];
            kr1 = *(const uint4*)&kbase[(size_t)(c1 + kkr + 32) * DM + khc];
            vr0 = *(const uint4*)&vbase[(size_t)(c1 + lane) * DM + wid * 16];
            vr1 = *(const uint4*)&vbase[(size_t)(c1 + lane) * DM + wid * 16 + 8];
        }

        f32x4 s[4];
#pragma unroll
        for (int ct = 0; ct < 4; ++ct) {
            f32x4 acc = (f32x4){0.f, 0.f, 0.f, 0.f};
            bf16x8 b0v = *(const bf16x8*)&Ks[16 * ct + l16][quad * 8];
            bf16x8 b1v = *(const bf16x8*)&Ks[16 * ct + l16][32 + quad * 8];
            acc = __builtin_amdgcn_mfma_f32_16x16x32_bf16(qa0, b0v, acc, 0, 0, 0);
            acc = __builtin_amdgcn_mfma_f32_16x16x32_bf16(qa1, b1v, acc, 0, 0, 0);
            s[ct] = acc;
        }
#pragma unroll
        for (int ct = 0; ct < 4; ++ct) {
            const bool kok = (c0 + 16 * ct + l16) < vl1;
#pragma unroll
            for (int r = 0; r < 4; ++r) {
                float e = exp2f(s[ct][r]);
                float p = kok ? e : 0.0f;
                p = rbad[r] ? 1.0f : p;
                s[ct][r] = p;
                suml[r] += p;
            }
        }
#pragma unroll
        for (int ct = 0; ct < 4; ++ct) {
            const int gidx = 2 * ct + (l16 >> 3);
            const int c = l16 & 7;
            const int gs = (gidx ^ quad) * 8 + c;
#pragma unroll
            for (int r = 0; r < 4; ++r)
                Ps[wid][quad * 4 + r][gs] = f2b(s[ct][r]);
        }
        bf16x8 pa0 = *(const bf16x8*)&Ps[wid][l16][(quad ^ k2) * 8];
        bf16x8 pa1 = *(const bf16x8*)&Ps[wid][l16][((4 + quad) ^ k2) * 8];
#pragma unroll
        for (int ct = 0; ct < 4; ++ct) {
            bf16x8 vb0 = *(const bf16x8*)&Vt[16 * ct + l16][quad * 8];
            bf16x8 vb1 = *(const bf16x8*)&Vt[16 * ct + l16][32 + quad * 8];
            o[ct] = __builtin_amdgcn_mfma_f32_16x16x32_bf16(pa0, vb0, o[ct], 0, 0, 0);
            o[ct] = __builtin_amdgcn_mfma_f32_16x16x32_bf16(pa1, vb1, o[ct], 0, 0, 0);
        }
        __syncthreads();
    }

#pragma unroll
    for (int d = 1; d < 16; d <<= 1) {
#pragma unroll
        for (int r = 0; r < 4; ++r) suml[r] += __shfl_xor(suml[r], d, 64);
    }
#pragma unroll
    for (int r = 0; r < 4; ++r) {
        float inv = 1.0f / suml[r];
        const size_t row = (size_t)(b * SEQ + q0 + 16 * wid + quad * 4 + r);
#pragma unroll
        for (int ct = 0; ct < 4; ++ct) {
            O[row * DM + h * HD + 16 * ct + l16] = f2b(o[ct][r] * inv);
        }
    }
}

// ---------------------------------------------------------------------------
// Kernel 3: row LayerNorm over D=768, fp32 in/out, IN PLACE on d_out.
// ---------------------------------------------------------------------------
__global__ __launch_bounds__(256) void ln_kernel(float* __restrict__ X,
                                                 const float* __restrict__ g,
                                                 const float* __restrict__ bvec) {
    __shared__ float red[256];
    const int row = blockIdx.x;
    const int t = threadIdx.x;
    float* xr = X + (size_t)row * DM;
    float x0 = xr[t];
    float x1 = xr[t + 256];
    float x2 = xr[t + 512];
    red[t] = x0 + x1 + x2;
    __syncthreads();
    for (int off = 128; off > 0; off >>= 1) {
        if (t < off) red[t] += red[t + off];
        __syncthreads();
    }
    float mu = red[0] * (1.0f / 768.0f);
    __syncthreads();
    float d0 = x0 - mu, d1 = x1 - mu, d2 = x2 - mu;
    red[t] = d0 * d0 + d1 * d1 + d2 * d2;
    __syncthreads();
    for (int off = 128; off > 0; off >>= 1) {
        if (t < off) red[t] += red[t + off];
        __syncthreads();
    }
    float rstd = rsqrtf(red[0] * (1.0f / 768.0f) + 1e-5f);
    xr[t]       = d0 * rstd * g[t]       + bvec[t];
    xr[t + 256] = d1 * rstd * g[t + 256] + bvec[t + 256];
    xr[t + 512] = d2 * rstd * g[t + 512] + bvec[t + 512];
}

// ---------------------------------------------------------------------------
extern "C" void kernel_launch(void* const* d_in, const int* in_sizes, int n_in,
                              void* d_out, int out_size, void* d_ws, size_t ws_size,
                              hipStream_t stream) {
    const float* queries = (const float*)d_in[0];
    const float* keys    = (const float*)d_in[1];
    const float* values  = (const float*)d_in[2];
    const int* mask1 = (const int*)d_in[3];
    const int* mask2 = (const int*)d_in[4];
    const float* Wq  = (const float*)d_in[5];
    const float* Wk  = (const float*)d_in[6];
    const float* Wv  = (const float*)d_in[7];
    const float* Wo  = (const float*)d_in[8];
    const float* d1w = (const float*)d_in[9];
    const float* d1b = (const float*)d_in[10];
    const float* d2w = (const float*)d_in[11];
    const float* d2b = (const float*)d_in[12];
    const float* lng = (const float*)d_in[13];
    const float* lnb = (const float*)d_in[14];

    // workspace: [lens 256B][b0][b1][b2][Wt x7][aq][ak][av]   (~84 MB)
    char* ws = (char*)d_ws;
    int* lens = (int*)ws;
    const size_t NB = (size_t)NROWS * DM * sizeof(unsigned short);   // 12.58 MB
    const size_t WT = (size_t)DM * DM;
    unsigned short* b0 = (unsigned short*)(ws + 256);
    unsigned short* b1 = (unsigned short*)(ws + 256 + NB);
    unsigned short* b2 = (unsigned short*)(ws + 256 + 2 * NB);
    unsigned short* wt = (unsigned short*)(ws + 256 + 3 * NB);       // 7 x 768*768
    unsigned short* aq = (unsigned short*)(ws + 256 + 3 * NB + 7 * WT * sizeof(unsigned short));
    unsigned short* ak = aq + (size_t)NROWS * DM;
    unsigned short* av = ak + (size_t)NROWS * DM;
    float* xout = (float*)d_out;

    // merged prep: weight cvt (z<6), wod1 + lens (z==6), input cvt (z>=7)
    prep_kernel<<<dim3(24, 24, 23), 256, 0, stream>>>(Wq, Wk, Wv, Wo, d1w, d2w,
                                                      wt, mask1, mask2, lens,
                                                      queries, keys, values,
                                                      aq, ak, av);

    // grouped QKV projection (Q output pre-scaled for exp2 softmax)
    qkv_gemm<<<dim3(64, 18), 256, 0, stream>>>(aq, ak, av, wt, b0, b1, b2);

    attn_mfma<<<16 * NH * BATCH, 256, 0, stream>>>(b0, b1, b2, b0, lens);  // O over Q

    // merged: mha -> b1, h = relu(attnout@Wod1 + d1b) -> b2
    gemm_mh<<<dim3(64, 12), 256, 0, stream>>>(b0, wt, b1, b2, d1b);

    // x = h @ d2w + d2b + mha -> d_out (fp32)
    gemm_bf<float><<<dim3(64, 6), 256, 0, stream>>>(b2, wt + 5 * WT, xout, d2b, b1, 0);

    ln_kernel<<<NROWS, 256, 0, stream>>>(xout, lng, lnb);  // in place
}

// Round 13
// 316.876 us; speedup vs baseline: 1.1559x; 1.0586x over previous
//
#include <hip/hip_runtime.h>
#include <hip/hip_bf16.h>
#include <type_traits>

// Problem constants (fixed by the reference)
#define DM   768
#define NH   12
#define HD   64
#define BATCH 8
#define SEQ  1024
#define NROWS (BATCH * SEQ)   // 8192

typedef short bf16x8 __attribute__((ext_vector_type(8)));
typedef float f32x4 __attribute__((ext_vector_type(4)));

// fp32 -> bf16 bits, round-half-up (2 VALU)
__device__ inline unsigned short f2b(float x) {
    union { float f; unsigned int u; } v; v.f = x;
    return (unsigned short)((v.u + 0x8000u) >> 16);
}
// pack two fp32 -> two bf16 (lo in low half): 2 v_add + 1 v_perm
__device__ inline unsigned int f2b2(float lo, float hi) {
    union { float f; unsigned int u; } a, b; a.f = lo; b.f = hi;
    return __builtin_amdgcn_perm(b.u + 0x8000u, a.u + 0x8000u, 0x07060302u);
}
// bf16 bits -> fp32
__device__ inline float b2f(unsigned short u) {
    union { float f; unsigned int x; } v; v.x = ((unsigned int)u) << 16;
    return v.f;
}

// async global->LDS, 16 B per lane; LDS dest = wave-uniform base + lane*16
__device__ inline void gld16(const unsigned short* g, unsigned short* l) {
    __builtin_amdgcn_global_load_lds(
        (const __attribute__((address_space(1))) unsigned int*)g,
        (__attribute__((address_space(3))) unsigned int*)l, 16, 0, 0);
}

// ---------------------------------------------------------------------------
// Kernel 0 (merged prep): z<6 -> weight convert+transpose; z==6 -> wod1 GEMM
// (x<12,y<12) + lens (y==12,x<16); z>=7 -> input fp32->bf16 convert planes.
// (round-11, passing)
// ---------------------------------------------------------------------------
__global__ __launch_bounds__(256) void prep_kernel(const float* __restrict__ w0,
                                                   const float* __restrict__ w1,
                                                   const float* __restrict__ w2,
                                                   const float* __restrict__ w3,
                                                   const float* __restrict__ w4,
                                                   const float* __restrict__ w5,
                                                   unsigned short* __restrict__ wt,
                                                   const int* __restrict__ m1,
                                                   const int* __restrict__ m2,
                                                   int* __restrict__ lens,
                                                   const float* __restrict__ qin,
                                                   const float* __restrict__ kin,
                                                   const float* __restrict__ vin,
                                                   unsigned short* __restrict__ oq,
                                                   unsigned short* __restrict__ ok,
                                                   unsigned short* __restrict__ ov) {
    const int z = blockIdx.z;
    const int t = threadIdx.x;

    if (z >= 7) {
        const int linear = (z - 7) * 576 + blockIdx.y * 24 + blockIdx.x;
        const int g = linear / 3072;
        const int r = linear % 3072;
        const float* src = (g == 0) ? qin : (g == 1) ? kin : vin;
        unsigned short* dst = (g == 0) ? oq : (g == 1) ? ok : ov;
        const size_t i = ((size_t)r * 256 + t) * 8;
        float4 f0 = ((const float4*)(src + i))[0];
        float4 f1 = ((const float4*)(src + i))[1];
        uint4 p;
        p.x = f2b2(f0.x, f0.y); p.y = f2b2(f0.z, f0.w);
        p.z = f2b2(f1.x, f1.y); p.w = f2b2(f1.z, f1.w);
        *(uint4*)(dst + i) = p;
        return;
    }

    if (z < 6) {
        __shared__ float tile[32][33];
        const float* W = (z == 0) ? w0 : (z == 1) ? w1 : (z == 2) ? w2
                       : (z == 3) ? w3 : (z == 4) ? w4 : w5;
        unsigned short* Wt = wt + (size_t)z * DM * DM;
        const int n0 = blockIdx.x * 32;
        const int k0 = blockIdx.y * 32;
        const int tx = t & 31;
        const int ty = t >> 5;
#pragma unroll
        for (int r = 0; r < 4; ++r)
            tile[ty + 8 * r][tx] = W[(size_t)(k0 + ty + 8 * r) * DM + n0 + tx];
        __syncthreads();
#pragma unroll
        for (int r = 0; r < 4; ++r)
            Wt[(size_t)(n0 + ty + 8 * r) * DM + k0 + tx] = f2b(tile[tx][ty + 8 * r]);
        return;
    }

    if (blockIdx.y == 12) {
        if (blockIdx.x >= 16) return;
        __shared__ int redi[256];
        const int bid = blockIdx.x;
        const int b = bid & 7;
        const int* m = (bid < 8) ? m1 : m2;
        int cnt = 0;
        for (int i = t; i < SEQ; i += 256) cnt += (m[b * SEQ + i] != 0) ? 1 : 0;
        redi[t] = cnt;
        __syncthreads();
        for (int off = 128; off > 0; off >>= 1) {
            if (t < off) redi[t] += redi[t + off];
            __syncthreads();
        }
        if (t == 0) lens[bid] = redi[0];
        return;
    }

    if (blockIdx.x >= 12 || blockIdx.y >= 12) return;
    {
        __shared__ __align__(16) unsigned short As[64][40];
        __shared__ __align__(16) unsigned short Bs[64][40];
        unsigned short* out = wt + (size_t)6 * DM * DM;
        const float* Wo = w3;
        const float* d1w = w4;
        const int mb = blockIdx.x * 64;
        const int nb = blockIdx.y * 64;
        const int wid = t >> 6, lane = t & 63;
        const int quad = lane >> 4, l16 = lane & 15;
        const int bk = t >> 3, bn = (t & 7) * 8;
        const int am = t >> 2, ak = (t & 3) * 8;

        f32x4 acc[4];
#pragma unroll
        for (int c = 0; c < 4; ++c) acc[c] = (f32x4){0.f, 0.f, 0.f, 0.f};

        for (int j0 = 0; j0 < DM; j0 += 32) {
            {
                const float* s = &d1w[(size_t)(j0 + bk) * DM + mb + bn];
                float4 f0 = ((const float4*)s)[0];
                float4 f1 = ((const float4*)s)[1];
                As[bn + 0][bk] = f2b(f0.x); As[bn + 1][bk] = f2b(f0.y);
                As[bn + 2][bk] = f2b(f0.z); As[bn + 3][bk] = f2b(f0.w);
                As[bn + 4][bk] = f2b(f1.x); As[bn + 5][bk] = f2b(f1.y);
                As[bn + 6][bk] = f2b(f1.z); As[bn + 7][bk] = f2b(f1.w);
            }
            {
                const float* s = &Wo[(size_t)(nb + am) * DM + j0 + ak];
                float4 f0 = ((const float4*)s)[0];
                float4 f1 = ((const float4*)s)[1];
                uint4 p;
                p.x = f2b2(f0.x, f0.y); p.y = f2b2(f0.z, f0.w);
                p.z = f2b2(f1.x, f1.y); p.w = f2b2(f1.z, f1.w);
                *(uint4*)&Bs[am][ak] = p;
            }
            __syncthreads();
            bf16x8 av = *(const bf16x8*)&As[16 * wid + l16][quad * 8];
#pragma unroll
            for (int c = 0; c < 4; ++c) {
                bf16x8 bv = *(const bf16x8*)&Bs[16 * c + l16][quad * 8];
                acc[c] = __builtin_amdgcn_mfma_f32_16x16x32_bf16(av, bv, acc[c], 0, 0, 0);
            }
            __syncthreads();
        }
#pragma unroll
        for (int c = 0; c < 4; ++c) {
            const int col = nb + 16 * c + l16;
#pragma unroll
            for (int r = 0; r < 4; ++r) {
                const int row = mb + 16 * wid + quad * 4 + r;
                out[(size_t)row * DM + col] = f2b(acc[c][r]);
            }
        }
    }
}

// ---------------------------------------------------------------------------
// Kernel 1a: grouped QKV GEMM (round-9 structure, passing). Q pre-scaled by
// 0.125*log2(e) for the exp2 softmax.
// ---------------------------------------------------------------------------
__global__ __launch_bounds__(256) void qkv_gemm(const unsigned short* __restrict__ aq,
                                                const unsigned short* __restrict__ akk,
                                                const unsigned short* __restrict__ av_,
                                                const unsigned short* __restrict__ wt,
                                                unsigned short* __restrict__ c0,
                                                unsigned short* __restrict__ c1,
                                                unsigned short* __restrict__ c2) {
    __shared__ __align__(16) unsigned short As[128][32];
    __shared__ __align__(16) unsigned short Ws[128][32];

    const int t = threadIdx.x;
    const int g = blockIdx.y / 6;
    const int m0 = blockIdx.x * 128;
    const int n0 = (blockIdx.y % 6) * 128;
    const unsigned short* A = (g == 0) ? aq : (g == 1) ? akk : av_;
    const unsigned short* Wt = wt + (size_t)g * DM * DM;
    unsigned short* C = (g == 0) ? c0 : (g == 1) ? c1 : c2;
    const float cs = (g == 0) ? 0.18033688f : 1.0f;   // 0.125*log2(e) for Q

    const int w = t >> 6, lane = t & 63;
    const int quad = lane >> 4, l16 = lane & 15;
    const int wm = w & 1, wn = w >> 1;
    const int srow = 16 * w + (lane >> 2);
    const int scol = 8 * (lane & 3);

    f32x4 acc[4][4];
#pragma unroll
    for (int i = 0; i < 4; ++i)
#pragma unroll
        for (int j = 0; j < 4; ++j) acc[i][j] = (f32x4){0.f, 0.f, 0.f, 0.f};

    for (int k0 = 0; k0 < DM; k0 += 32) {
#pragma unroll
        for (int j = 0; j < 2; ++j) {
            gld16(&A[(size_t)(m0 + srow + 64 * j) * DM + k0 + scol],
                  &As[16 * w + 64 * j][0]);
            gld16(&Wt[(size_t)(n0 + srow + 64 * j) * DM + k0 + scol],
                  &Ws[16 * w + 64 * j][0]);
        }
        __syncthreads();

        bf16x8 av[4], bv[4];
#pragma unroll
        for (int i = 0; i < 4; ++i)
            av[i] = *(const bf16x8*)&As[wm * 64 + 16 * i + l16][quad * 8];
#pragma unroll
        for (int i = 0; i < 4; ++i)
            bv[i] = *(const bf16x8*)&Ws[wn * 64 + 16 * i + l16][quad * 8];
#pragma unroll
        for (int i = 0; i < 4; ++i)
#pragma unroll
            for (int j = 0; j < 4; ++j)
                acc[i][j] = __builtin_amdgcn_mfma_f32_16x16x32_bf16(av[i], bv[j], acc[i][j], 0, 0, 0);
        __syncthreads();
    }

#pragma unroll
    for (int i = 0; i < 4; ++i)
#pragma unroll
        for (int j = 0; j < 4; ++j) {
            const int gn = n0 + wn * 64 + 16 * j + l16;
#pragma unroll
            for (int r = 0; r < 4; ++r) {
                const int gm = m0 + wm * 64 + 16 * i + quad * 4 + r;
                C[(size_t)gm * DM + gn] = f2b(acc[i][j][r] * cs);
            }
        }
}

// ---------------------------------------------------------------------------
// Kernel 1a': per-(b,h) V column partial sums (8 chunks of 128 seq rows).
// vp[(bh*8+chunk)*64 + d] = sum over 128 rows of Vproj[b, rows, h*64+d].
// Feeds the uniform-softmax (masked-row) mean path in attention.
// ---------------------------------------------------------------------------
__global__ __launch_bounds__(256) void vpart_kernel(const unsigned short* __restrict__ v,
                                                    float* __restrict__ vp) {
    __shared__ float red[4][64];
    const int t = threadIdx.x;
    const int bh = blockIdx.x;           // 96
    const int chunk = blockIdx.y;        // 8
    const int b = bh / NH, h = bh % NH;
    const int d = t & 63, rg = t >> 6;   // 4 row groups of 32
    const unsigned short* base =
        v + (size_t)(b * SEQ + chunk * 128 + rg * 32) * DM + h * HD + d;
    float s = 0.0f;
#pragma unroll 4
    for (int i = 0; i < 32; ++i) s += b2f(base[(size_t)i * DM]);
    red[rg][d] = s;
    __syncthreads();
    if (rg == 0)
        vp[((size_t)bh * 8 + chunk) * 64 + d] = red[0][d] + red[1][d] + red[2][d] + red[3][d];
}

// ---------------------------------------------------------------------------
// Kernel 1b: bf16 GEMM 128x128, gld16 both operands (round-9, passing).
// ---------------------------------------------------------------------------
template <typename CT>
__global__ __launch_bounds__(256) void gemm_bf(const unsigned short* __restrict__ A,
                                               const unsigned short* __restrict__ Wt,
                                               CT* __restrict__ C,
                                               const float* __restrict__ bias,
                                               const unsigned short* __restrict__ res,
                                               int relu) {
    __shared__ __align__(16) unsigned short As[128][32];
    __shared__ __align__(16) unsigned short Ws[128][32];

    const int t = threadIdx.x;
    const int m0 = blockIdx.x * 128;
    const int n0 = blockIdx.y * 128;
    const int w = t >> 6, lane = t & 63;
    const int quad = lane >> 4, l16 = lane & 15;
    const int wm = w & 1, wn = w >> 1;
    const int srow = 16 * w + (lane >> 2);
    const int scol = 8 * (lane & 3);

    f32x4 acc[4][4];
#pragma unroll
    for (int i = 0; i < 4; ++i)
#pragma unroll
        for (int j = 0; j < 4; ++j) acc[i][j] = (f32x4){0.f, 0.f, 0.f, 0.f};

    for (int k0 = 0; k0 < DM; k0 += 32) {
#pragma unroll
        for (int j = 0; j < 2; ++j) {
            gld16(&A[(size_t)(m0 + srow + 64 * j) * DM + k0 + scol],
                  &As[16 * w + 64 * j][0]);
            gld16(&Wt[(size_t)(n0 + srow + 64 * j) * DM + k0 + scol],
                  &Ws[16 * w + 64 * j][0]);
        }
        __syncthreads();

        bf16x8 av[4], bv[4];
#pragma unroll
        for (int i = 0; i < 4; ++i)
            av[i] = *(const bf16x8*)&As[wm * 64 + 16 * i + l16][quad * 8];
#pragma unroll
        for (int i = 0; i < 4; ++i)
            bv[i] = *(const bf16x8*)&Ws[wn * 64 + 16 * i + l16][quad * 8];
#pragma unroll
        for (int i = 0; i < 4; ++i)
#pragma unroll
            for (int j = 0; j < 4; ++j)
                acc[i][j] = __builtin_amdgcn_mfma_f32_16x16x32_bf16(av[i], bv[j], acc[i][j], 0, 0, 0);
        __syncthreads();
    }

#pragma unroll
    for (int i = 0; i < 4; ++i)
#pragma unroll
        for (int j = 0; j < 4; ++j) {
            const int gn = n0 + wn * 64 + 16 * j + l16;
            const float badd = bias ? bias[gn] : 0.0f;
#pragma unroll
            for (int r = 0; r < 4; ++r) {
                const int gm = m0 + wm * 64 + 16 * i + quad * 4 + r;
                float cv = acc[i][j][r] + badd;
                if (relu) cv = fmaxf(cv, 0.0f);
                if (res) cv += b2f(res[(size_t)gm * DM + gn]);
                if constexpr (std::is_same<CT, float>::value) {
                    C[(size_t)gm * DM + gn] = cv;
                } else {
                    C[(size_t)gm * DM + gn] = f2b(cv);
                }
            }
        }
}

// ---------------------------------------------------------------------------
// Kernel 1c: merged mha + ffn-hidden GEMM (round-9, passing).
// ---------------------------------------------------------------------------
__global__ __launch_bounds__(256) void gemm_mh(const unsigned short* __restrict__ A,
                                               const unsigned short* __restrict__ wt,
                                               unsigned short* __restrict__ cm,
                                               unsigned short* __restrict__ ch,
                                               const float* __restrict__ d1b) {
    __shared__ __align__(16) unsigned short As[128][32];
    __shared__ __align__(16) unsigned short Ws[128][32];

    const int t = threadIdx.x;
    const int unit = blockIdx.y / 6;
    const unsigned short* Wt = wt + (size_t)(unit ? 6 : 3) * DM * DM;
    unsigned short* C = unit ? ch : cm;
    const int m0 = blockIdx.x * 128;
    const int n0 = (blockIdx.y % 6) * 128;
    const int w = t >> 6, lane = t & 63;
    const int quad = lane >> 4, l16 = lane & 15;
    const int wm = w & 1, wn = w >> 1;
    const int srow = 16 * w + (lane >> 2);
    const int scol = 8 * (lane & 3);

    f32x4 acc[4][4];
#pragma unroll
    for (int i = 0; i < 4; ++i)
#pragma unroll
        for (int j = 0; j < 4; ++j) acc[i][j] = (f32x4){0.f, 0.f, 0.f, 0.f};

    for (int k0 = 0; k0 < DM; k0 += 32) {
#pragma unroll
        for (int j = 0; j < 2; ++j) {
            gld16(&A[(size_t)(m0 + srow + 64 * j) * DM + k0 + scol],
                  &As[16 * w + 64 * j][0]);
            gld16(&Wt[(size_t)(n0 + srow + 64 * j) * DM + k0 + scol],
                  &Ws[16 * w + 64 * j][0]);
        }
        __syncthreads();

        bf16x8 av[4], bv[4];
#pragma unroll
        for (int i = 0; i < 4; ++i)
            av[i] = *(const bf16x8*)&As[wm * 64 + 16 * i + l16][quad * 8];
#pragma unroll
        for (int i = 0; i < 4; ++i)
            bv[i] = *(const bf16x8*)&Ws[wn * 64 + 16 * i + l16][quad * 8];
#pragma unroll
        for (int i = 0; i < 4; ++i)
#pragma unroll
            for (int j = 0; j < 4; ++j)
                acc[i][j] = __builtin_amdgcn_mfma_f32_16x16x32_bf16(av[i], bv[j], acc[i][j], 0, 0, 0);
        __syncthreads();
    }

#pragma unroll
    for (int i = 0; i < 4; ++i)
#pragma unroll
        for (int j = 0; j < 4; ++j) {
            const int gn = n0 + wn * 64 + 16 * j + l16;
            const float badd = unit ? d1b[gn] : 0.0f;
#pragma unroll
            for (int r = 0; r < 4; ++r) {
                const int gm = m0 + wm * 64 + 16 * i + quad * 4 + r;
                float cv = acc[i][j][r] + badd;
                if (unit) cv = fmaxf(cv, 0.0f);
                C[(size_t)gm * DM + gn] = f2b(cv);
            }
        }
}

// ---------------------------------------------------------------------------
// Kernel 2: MFMA flash attention (round-9 body) + mask-aware work skipping:
//  - blocks with q0 >= vl2 (or vl1==0): every row gets the reference's
//    uniform softmax = column-mean of V -> write precomputed mean, return.
//  - key-tile loop runs only nt = ceil(vl1/64) tiles (keys >= vl1 have p=0).
//  - straddling rows (q >= vl2) get the mean in the epilogue.
//  - exp is the raw v_exp_f32 (__builtin_amdgcn_exp2f); Q pre-scaled.
// O written in place over Q (regions disjoint per block).
// ---------------------------------------------------------------------------
__global__ __launch_bounds__(256) void attn_mfma(const unsigned short* Q,
                                                 const unsigned short* __restrict__ K,
                                                 const unsigned short* __restrict__ V,
                                                 unsigned short* O,
                                                 const int* __restrict__ lens,
                                                 const float* __restrict__ vp) {
    __shared__ __align__(16) unsigned short Ks[64][72];
    __shared__ __align__(16) unsigned short Vt[64][72];
    __shared__ __align__(16) unsigned short Ps[4][16][72];

    const int t = threadIdx.x;
    const int bid = blockIdx.x;
    const int q0 = (bid & 15) * 64;
    const int h = (bid >> 4) % NH;
    const int b = bid / (16 * NH);
    const int vl1 = lens[b];
    const int vl2 = lens[8 + b];
    const int wid = t >> 6;
    const int lane = t & 63;
    const int quad = lane >> 4;
    const int l16 = lane & 15;
    const size_t vpb = (size_t)(b * NH + h) * 8 * 64;

    // Fully-masked block: all rows = uniform mean of V. No QK^T/PV at all.
    if (q0 >= vl2 || vl1 == 0) {
        float vm[4];
#pragma unroll
        for (int ct = 0; ct < 4; ++ct) {
            float s = 0.0f;
#pragma unroll
            for (int c = 0; c < 8; ++c) s += vp[vpb + (size_t)c * 64 + 16 * ct + l16];
            vm[ct] = s * (1.0f / 1024.0f);
        }
#pragma unroll
        for (int r = 0; r < 4; ++r) {
            const size_t row = (size_t)(b * SEQ + q0 + 16 * wid + quad * 4 + r);
#pragma unroll
            for (int ct = 0; ct < 4; ++ct)
                O[row * DM + h * HD + 16 * ct + l16] = f2b(vm[ct]);
        }
        return;
    }

    bf16x8 qa0, qa1;
    {
        const unsigned short* qp =
            &Q[(size_t)(b * SEQ + q0 + 16 * wid + l16) * DM + h * HD + quad * 8];
        qa0 = *(const bf16x8*)qp;
        qa1 = *(const bf16x8*)(qp + 32);
    }

    f32x4 o[4];
#pragma unroll
    for (int ct = 0; ct < 4; ++ct) o[ct] = (f32x4){0.f, 0.f, 0.f, 0.f};
    float suml[4];
    bool rbad[4];
#pragma unroll
    for (int r = 0; r < 4; ++r) {
        suml[r] = 0.0f;
        rbad[r] = (q0 + 16 * wid + quad * 4 + r) >= vl2;
    }

    const int nt = (vl1 + 63) >> 6;   // 1..16 key tiles carry nonzero p

    const int kkr = t >> 3;
    const int khc = (t & 7) * 8;
    const unsigned short* kbase = &K[(size_t)(b * SEQ) * DM + h * HD];
    const unsigned short* vbase = &V[(size_t)(b * SEQ) * DM + h * HD];

    uint4 kr0 = *(const uint4*)&kbase[(size_t)kkr * DM + khc];
    uint4 kr1 = *(const uint4*)&kbase[(size_t)(kkr + 32) * DM + khc];
    uint4 vr0 = *(const uint4*)&vbase[(size_t)lane * DM + wid * 16];
    uint4 vr1 = *(const uint4*)&vbase[(size_t)lane * DM + wid * 16 + 8];

    const int k2 = l16 >> 2;

    for (int tile = 0; tile < nt; ++tile) {
        const int c0 = tile * 64;
        *(uint4*)&Ks[kkr][khc] = kr0;
        *(uint4*)&Ks[kkr + 32][khc] = kr1;
        {
            union { uint4 u; unsigned short s[8]; } va, vb;
            va.u = vr0; vb.u = vr1;
#pragma unroll
            for (int j = 0; j < 8; ++j) Vt[wid * 16 + j][lane] = va.s[j];
#pragma unroll
            for (int j = 0; j < 8; ++j) Vt[wid * 16 + 8 + j][lane] = vb.s[j];
        }
        __syncthreads();

        if (tile < nt - 1) {
            const int c1 = c0 + 64;
            kr0 = *(const uint4*)&kbase[(size_t)(c1 + kkr) * DM + khc];
            kr1 = *(const uint4*)&kbase[(size_t)(c1 + kkr + 32) * DM + khc];
            vr0 = *(const uint4*)&vbase[(size_t)(c1 + lane) * DM + wid * 16];
            vr1 = *(const uint4*)&vbase[(size_t)(c1 + lane) * DM + wid * 16 + 8];
        }

        f32x4 s[4];
#pragma unroll
        for (int ct = 0; ct < 4; ++ct) {
            f32x4 acc = (f32x4){0.f, 0.f, 0.f, 0.f};
            bf16x8 b0v = *(const bf16x8*)&Ks[16 * ct + l16][quad * 8];
            bf16x8 b1v = *(const bf16x8*)&Ks[16 * ct + l16][32 + quad * 8];
            acc = __builtin_amdgcn_mfma_f32_16x16x32_bf16(qa0, b0v, acc, 0, 0, 0);
            acc = __builtin_amdgcn_mfma_f32_16x16x32_bf16(qa1, b1v, acc, 0, 0, 0);
            s[ct] = acc;
        }
#pragma unroll
        for (int ct = 0; ct < 4; ++ct) {
            const bool kok = (c0 + 16 * ct + l16) < vl1;
#pragma unroll
            for (int r = 0; r < 4; ++r) {
                float e = __builtin_amdgcn_exp2f(s[ct][r]);
                float p = kok ? e : 0.0f;
                s[ct][r] = p;
                suml[r] += p;
            }
        }
#pragma unroll
        for (int ct = 0; ct < 4; ++ct) {
            const int gidx = 2 * ct + (l16 >> 3);
            const int c = l16 & 7;
            const int gs = (gidx ^ quad) * 8 + c;
#pragma unroll
            for (int r = 0; r < 4; ++r)
                Ps[wid][quad * 4 + r][gs] = f2b(s[ct][r]);
        }
        bf16x8 pa0 = *(const bf16x8*)&Ps[wid][l16][(quad ^ k2) * 8];
        bf16x8 pa1 = *(const bf16x8*)&Ps[wid][l16][((4 + quad) ^ k2) * 8];
#pragma unroll
        for (int ct = 0; ct < 4; ++ct) {
            bf16x8 vb0 = *(const bf16x8*)&Vt[16 * ct + l16][quad * 8];
            bf16x8 vb1 = *(const bf16x8*)&Vt[16 * ct + l16][32 + quad * 8];
            o[ct] = __builtin_amdgcn_mfma_f32_16x16x32_bf16(pa0, vb0, o[ct], 0, 0, 0);
            o[ct] = __builtin_amdgcn_mfma_f32_16x16x32_bf16(pa1, vb1, o[ct], 0, 0, 0);
        }
        __syncthreads();
    }

#pragma unroll
    for (int d = 1; d < 16; d <<= 1) {
#pragma unroll
        for (int r = 0; r < 4; ++r) suml[r] += __shfl_xor(suml[r], d, 64);
    }

    // lazy mean for straddling rbad rows
    float vm[4];
    if (rbad[0] || rbad[3]) {
#pragma unroll
        for (int ct = 0; ct < 4; ++ct) {
            float s = 0.0f;
#pragma unroll
            for (int c = 0; c < 8; ++c) s += vp[vpb + (size_t)c * 64 + 16 * ct + l16];
            vm[ct] = s * (1.0f / 1024.0f);
        }
    }
#pragma unroll
    for (int r = 0; r < 4; ++r) {
        const float inv = 1.0f / suml[r];
        const size_t row = (size_t)(b * SEQ + q0 + 16 * wid + quad * 4 + r);
#pragma unroll
        for (int ct = 0; ct < 4; ++ct) {
            const float val = rbad[r] ? vm[ct] : o[ct][r] * inv;
            O[row * DM + h * HD + 16 * ct + l16] = f2b(val);
        }
    }
}

// ---------------------------------------------------------------------------
// Kernel 3: row LayerNorm over D=768, fp32 in/out, IN PLACE on d_out.
// ---------------------------------------------------------------------------
__global__ __launch_bounds__(256) void ln_kernel(float* __restrict__ X,
                                                 const float* __restrict__ g,
                                                 const float* __restrict__ bvec) {
    __shared__ float red[256];
    const int row = blockIdx.x;
    const int t = threadIdx.x;
    float* xr = X + (size_t)row * DM;
    float x0 = xr[t];
    float x1 = xr[t + 256];
    float x2 = xr[t + 512];
    red[t] = x0 + x1 + x2;
    __syncthreads();
    for (int off = 128; off > 0; off >>= 1) {
        if (t < off) red[t] += red[t + off];
        __syncthreads();
    }
    float mu = red[0] * (1.0f / 768.0f);
    __syncthreads();
    float d0 = x0 - mu, d1 = x1 - mu, d2 = x2 - mu;
    red[t] = d0 * d0 + d1 * d1 + d2 * d2;
    __syncthreads();
    for (int off = 128; off > 0; off >>= 1) {
        if (t < off) red[t] += red[t + off];
        __syncthreads();
    }
    float rstd = rsqrtf(red[0] * (1.0f / 768.0f) + 1e-5f);
    xr[t]       = d0 * rstd * g[t]       + bvec[t];
    xr[t + 256] = d1 * rstd * g[t + 256] + bvec[t + 256];
    xr[t + 512] = d2 * rstd * g[t + 512] + bvec[t + 512];
}

// ---------------------------------------------------------------------------
extern "C" void kernel_launch(void* const* d_in, const int* in_sizes, int n_in,
                              void* d_out, int out_size, void* d_ws, size_t ws_size,
                              hipStream_t stream) {
    const float* queries = (const float*)d_in[0];
    const float* keys    = (const float*)d_in[1];
    const float* values  = (const float*)d_in[2];
    const int* mask1 = (const int*)d_in[3];
    const int* mask2 = (const int*)d_in[4];
    const float* Wq  = (const float*)d_in[5];
    const float* Wk  = (const float*)d_in[6];
    const float* Wv  = (const float*)d_in[7];
    const float* Wo  = (const float*)d_in[8];
    const float* d1w = (const float*)d_in[9];
    const float* d1b = (const float*)d_in[10];
    const float* d2w = (const float*)d_in[11];
    const float* d2b = (const float*)d_in[12];
    const float* lng = (const float*)d_in[13];
    const float* lnb = (const float*)d_in[14];

    // workspace: [lens 256B][vp 192KB][b0][b1][b2][Wt x7][aq][ak][av]  (~84 MB)
    char* ws = (char*)d_ws;
    int* lens = (int*)ws;
    float* vp = (float*)(ws + 256);                                  // 96*8*64 fp32
    const size_t VP = (size_t)96 * 8 * 64 * sizeof(float);
    const size_t NB = (size_t)NROWS * DM * sizeof(unsigned short);   // 12.58 MB
    const size_t WT = (size_t)DM * DM;
    unsigned short* b0 = (unsigned short*)(ws + 256 + VP);
    unsigned short* b1 = (unsigned short*)(ws + 256 + VP + NB);
    unsigned short* b2 = (unsigned short*)(ws + 256 + VP + 2 * NB);
    unsigned short* wt = (unsigned short*)(ws + 256 + VP + 3 * NB);  // 7 x 768*768
    unsigned short* aq = (unsigned short*)(ws + 256 + VP + 3 * NB + 7 * WT * sizeof(unsigned short));
    unsigned short* ak = aq + (size_t)NROWS * DM;
    unsigned short* av = ak + (size_t)NROWS * DM;
    float* xout = (float*)d_out;

    // merged prep: weight cvt (z<6), wod1 + lens (z==6), input cvt (z>=7)
    prep_kernel<<<dim3(24, 24, 23), 256, 0, stream>>>(Wq, Wk, Wv, Wo, d1w, d2w,
                                                      wt, mask1, mask2, lens,
                                                      queries, keys, values,
                                                      aq, ak, av);

    // grouped QKV projection (Q output pre-scaled for exp2 softmax)
    qkv_gemm<<<dim3(64, 18), 256, 0, stream>>>(aq, ak, av, wt, b0, b1, b2);

    // per-(b,h) V column partial sums for the uniform-softmax mean path
    vpart_kernel<<<dim3(96, 8), 256, 0, stream>>>(b2, vp);

    attn_mfma<<<16 * NH * BATCH, 256, 0, stream>>>(b0, b1, b2, b0, lens, vp);  // O over Q

    // merged: mha -> b1, h = relu(attnout@Wod1 + d1b) -> b2
    gemm_mh<<<dim3(64, 12), 256, 0, stream>>>(b0, wt, b1, b2, d1b);

    // x = h @ d2w + d2b + mha -> d_out (fp32)
    gemm_bf<float><<<dim3(64, 6), 256, 0, stream>>>(b2, wt + 5 * WT, xout, d2b, b1, 0);

    ln_kernel<<<NROWS, 256, 0, stream>>>(xout, lng, lnb);  // in place
}

// Round 14
// 310.429 us; speedup vs baseline: 1.1799x; 1.0208x over previous
//
#include <hip/hip_runtime.h>
#include <hip/hip_bf16.h>
#include <type_traits>

// Problem constants (fixed by the reference)
#define DM   768
#define NH   12
#define HD   64
#define BATCH 8
#define SEQ  1024
#define NROWS (BATCH * SEQ)   // 8192

typedef short bf16x8 __attribute__((ext_vector_type(8)));
typedef float f32x4 __attribute__((ext_vector_type(4)));

// fp32 -> bf16 bits, round-half-up (2 VALU)
__device__ inline unsigned short f2b(float x) {
    union { float f; unsigned int u; } v; v.f = x;
    return (unsigned short)((v.u + 0x8000u) >> 16);
}
// pack two fp32 -> two bf16 (lo in low half): 2 v_add + 1 v_perm
__device__ inline unsigned int f2b2(float lo, float hi) {
    union { float f; unsigned int u; } a, b; a.f = lo; b.f = hi;
    return __builtin_amdgcn_perm(b.u + 0x8000u, a.u + 0x8000u, 0x07060302u);
}
// bf16 bits -> fp32
__device__ inline float b2f(unsigned short u) {
    union { float f; unsigned int x; } v; v.x = ((unsigned int)u) << 16;
    return v.f;
}

// async global->LDS, 16 B per lane; LDS dest = wave-uniform base + lane*16
__device__ inline void gld16(const unsigned short* g, unsigned short* l) {
    __builtin_amdgcn_global_load_lds(
        (const __attribute__((address_space(1))) unsigned int*)g,
        (__attribute__((address_space(3))) unsigned int*)l, 16, 0, 0);
}

// ---------------------------------------------------------------------------
// Kernel 0 (merged prep): z<6 -> weight convert+transpose; z==6 -> wod1 GEMM
// (x<12,y<12) + lens (y==12,x<16); z>=7 -> input fp32->bf16 convert planes.
// (round-11, passing)
// ---------------------------------------------------------------------------
__global__ __launch_bounds__(256) void prep_kernel(const float* __restrict__ w0,
                                                   const float* __restrict__ w1,
                                                   const float* __restrict__ w2,
                                                   const float* __restrict__ w3,
                                                   const float* __restrict__ w4,
                                                   const float* __restrict__ w5,
                                                   unsigned short* __restrict__ wt,
                                                   const int* __restrict__ m1,
                                                   const int* __restrict__ m2,
                                                   int* __restrict__ lens,
                                                   const float* __restrict__ qin,
                                                   const float* __restrict__ kin,
                                                   const float* __restrict__ vin,
                                                   unsigned short* __restrict__ oq,
                                                   unsigned short* __restrict__ ok,
                                                   unsigned short* __restrict__ ov) {
    const int z = blockIdx.z;
    const int t = threadIdx.x;

    if (z >= 7) {
        const int linear = (z - 7) * 576 + blockIdx.y * 24 + blockIdx.x;
        const int g = linear / 3072;
        const int r = linear % 3072;
        const float* src = (g == 0) ? qin : (g == 1) ? kin : vin;
        unsigned short* dst = (g == 0) ? oq : (g == 1) ? ok : ov;
        const size_t i = ((size_t)r * 256 + t) * 8;
        float4 f0 = ((const float4*)(src + i))[0];
        float4 f1 = ((const float4*)(src + i))[1];
        uint4 p;
        p.x = f2b2(f0.x, f0.y); p.y = f2b2(f0.z, f0.w);
        p.z = f2b2(f1.x, f1.y); p.w = f2b2(f1.z, f1.w);
        *(uint4*)(dst + i) = p;
        return;
    }

    if (z < 6) {
        __shared__ float tile[32][33];
        const float* W = (z == 0) ? w0 : (z == 1) ? w1 : (z == 2) ? w2
                       : (z == 3) ? w3 : (z == 4) ? w4 : w5;
        unsigned short* Wt = wt + (size_t)z * DM * DM;
        const int n0 = blockIdx.x * 32;
        const int k0 = blockIdx.y * 32;
        const int tx = t & 31;
        const int ty = t >> 5;
#pragma unroll
        for (int r = 0; r < 4; ++r)
            tile[ty + 8 * r][tx] = W[(size_t)(k0 + ty + 8 * r) * DM + n0 + tx];
        __syncthreads();
#pragma unroll
        for (int r = 0; r < 4; ++r)
            Wt[(size_t)(n0 + ty + 8 * r) * DM + k0 + tx] = f2b(tile[tx][ty + 8 * r]);
        return;
    }

    if (blockIdx.y == 12) {
        if (blockIdx.x >= 16) return;
        __shared__ int redi[256];
        const int bid = blockIdx.x;
        const int b = bid & 7;
        const int* m = (bid < 8) ? m1 : m2;
        int cnt = 0;
        for (int i = t; i < SEQ; i += 256) cnt += (m[b * SEQ + i] != 0) ? 1 : 0;
        redi[t] = cnt;
        __syncthreads();
        for (int off = 128; off > 0; off >>= 1) {
            if (t < off) redi[t] += redi[t + off];
            __syncthreads();
        }
        if (t == 0) lens[bid] = redi[0];
        return;
    }

    if (blockIdx.x >= 12 || blockIdx.y >= 12) return;
    {
        __shared__ __align__(16) unsigned short As[64][40];
        __shared__ __align__(16) unsigned short Bs[64][40];
        unsigned short* out = wt + (size_t)6 * DM * DM;
        const float* Wo = w3;
        const float* d1w = w4;
        const int mb = blockIdx.x * 64;
        const int nb = blockIdx.y * 64;
        const int wid = t >> 6, lane = t & 63;
        const int quad = lane >> 4, l16 = lane & 15;
        const int bk = t >> 3, bn = (t & 7) * 8;
        const int am = t >> 2, ak = (t & 3) * 8;

        f32x4 acc[4];
#pragma unroll
        for (int c = 0; c < 4; ++c) acc[c] = (f32x4){0.f, 0.f, 0.f, 0.f};

        for (int j0 = 0; j0 < DM; j0 += 32) {
            {
                const float* s = &d1w[(size_t)(j0 + bk) * DM + mb + bn];
                float4 f0 = ((const float4*)s)[0];
                float4 f1 = ((const float4*)s)[1];
                As[bn + 0][bk] = f2b(f0.x); As[bn + 1][bk] = f2b(f0.y);
                As[bn + 2][bk] = f2b(f0.z); As[bn + 3][bk] = f2b(f0.w);
                As[bn + 4][bk] = f2b(f1.x); As[bn + 5][bk] = f2b(f1.y);
                As[bn + 6][bk] = f2b(f1.z); As[bn + 7][bk] = f2b(f1.w);
            }
            {
                const float* s = &Wo[(size_t)(nb + am) * DM + j0 + ak];
                float4 f0 = ((const float4*)s)[0];
                float4 f1 = ((const float4*)s)[1];
                uint4 p;
                p.x = f2b2(f0.x, f0.y); p.y = f2b2(f0.z, f0.w);
                p.z = f2b2(f1.x, f1.y); p.w = f2b2(f1.z, f1.w);
                *(uint4*)&Bs[am][ak] = p;
            }
            __syncthreads();
            bf16x8 av = *(const bf16x8*)&As[16 * wid + l16][quad * 8];
#pragma unroll
            for (int c = 0; c < 4; ++c) {
                bf16x8 bv = *(const bf16x8*)&Bs[16 * c + l16][quad * 8];
                acc[c] = __builtin_amdgcn_mfma_f32_16x16x32_bf16(av, bv, acc[c], 0, 0, 0);
            }
            __syncthreads();
        }
#pragma unroll
        for (int c = 0; c < 4; ++c) {
            const int col = nb + 16 * c + l16;
#pragma unroll
            for (int r = 0; r < 4; ++r) {
                const int row = mb + 16 * wid + quad * 4 + r;
                out[(size_t)row * DM + col] = f2b(acc[c][r]);
            }
        }
    }
}

// ---------------------------------------------------------------------------
// Kernel 1a: grouped QKV GEMM. Round-14: XOR-swizzled LDS 16B groups kill the
// 8-way ds_read_b128 bank conflicts (bank start was 16*(l16&1)+4*quad — 8
// lanes/start; now ^((l16>>1)&3) spreads to 2 lanes/start = free). Store side
// stays gld16-legal: lane fetches global group (lane&3)^((lane>>3)&3).
// Q pre-scaled by 0.125*log2(e) for the exp2 softmax.
// ---------------------------------------------------------------------------
__global__ __launch_bounds__(256) void qkv_gemm(const unsigned short* __restrict__ aq,
                                                const unsigned short* __restrict__ akk,
                                                const unsigned short* __restrict__ av_,
                                                const unsigned short* __restrict__ wt,
                                                unsigned short* __restrict__ c0,
                                                unsigned short* __restrict__ c1,
                                                unsigned short* __restrict__ c2) {
    __shared__ __align__(16) unsigned short As[128][32];
    __shared__ __align__(16) unsigned short Ws[128][32];

    const int t = threadIdx.x;
    const int g = blockIdx.y / 6;
    const int m0 = blockIdx.x * 128;
    const int n0 = (blockIdx.y % 6) * 128;
    const unsigned short* A = (g == 0) ? aq : (g == 1) ? akk : av_;
    const unsigned short* Wt = wt + (size_t)g * DM * DM;
    unsigned short* C = (g == 0) ? c0 : (g == 1) ? c1 : c2;
    const float cs = (g == 0) ? 0.18033688f : 1.0f;   // 0.125*log2(e) for Q

    const int w = t >> 6, lane = t & 63;
    const int quad = lane >> 4, l16 = lane & 15;
    const int wm = w & 1, wn = w >> 1;
    const int srow = 16 * w + (lane >> 2);
    const int scol = 8 * ((lane & 3) ^ ((lane >> 3) & 3));    // swizzled fetch group
    const int swr = (quad ^ ((l16 >> 1) & 3)) * 8;            // fragment read slot

    f32x4 acc[4][4];
#pragma unroll
    for (int i = 0; i < 4; ++i)
#pragma unroll
        for (int j = 0; j < 4; ++j) acc[i][j] = (f32x4){0.f, 0.f, 0.f, 0.f};

    for (int k0 = 0; k0 < DM; k0 += 32) {
#pragma unroll
        for (int j = 0; j < 2; ++j) {
            gld16(&A[(size_t)(m0 + srow + 64 * j) * DM + k0 + scol],
                  &As[16 * w + 64 * j][0]);
            gld16(&Wt[(size_t)(n0 + srow + 64 * j) * DM + k0 + scol],
                  &Ws[16 * w + 64 * j][0]);
        }
        __syncthreads();

        bf16x8 av[4], bv[4];
#pragma unroll
        for (int i = 0; i < 4; ++i)
            av[i] = *(const bf16x8*)&As[wm * 64 + 16 * i + l16][swr];
#pragma unroll
        for (int i = 0; i < 4; ++i)
            bv[i] = *(const bf16x8*)&Ws[wn * 64 + 16 * i + l16][swr];
#pragma unroll
        for (int i = 0; i < 4; ++i)
#pragma unroll
            for (int j = 0; j < 4; ++j)
                acc[i][j] = __builtin_amdgcn_mfma_f32_16x16x32_bf16(av[i], bv[j], acc[i][j], 0, 0, 0);
        __syncthreads();
    }

#pragma unroll
    for (int i = 0; i < 4; ++i)
#pragma unroll
        for (int j = 0; j < 4; ++j) {
            const int gn = n0 + wn * 64 + 16 * j + l16;
#pragma unroll
            for (int r = 0; r < 4; ++r) {
                const int gm = m0 + wm * 64 + 16 * i + quad * 4 + r;
                C[(size_t)gm * DM + gn] = f2b(acc[i][j][r] * cs);
            }
        }
}

// ---------------------------------------------------------------------------
// Kernel 1a': per-(b,h) V column partial sums (round-13, passing).
// ---------------------------------------------------------------------------
__global__ __launch_bounds__(256) void vpart_kernel(const unsigned short* __restrict__ v,
                                                    float* __restrict__ vp) {
    __shared__ float red[4][64];
    const int t = threadIdx.x;
    const int bh = blockIdx.x;           // 96
    const int chunk = blockIdx.y;        // 8
    const int b = bh / NH, h = bh % NH;
    const int d = t & 63, rg = t >> 6;   // 4 row groups of 32
    const unsigned short* base =
        v + (size_t)(b * SEQ + chunk * 128 + rg * 32) * DM + h * HD + d;
    float s = 0.0f;
#pragma unroll 4
    for (int i = 0; i < 32; ++i) s += b2f(base[(size_t)i * DM]);
    red[rg][d] = s;
    __syncthreads();
    if (rg == 0)
        vp[((size_t)bh * 8 + chunk) * 64 + d] = red[0][d] + red[1][d] + red[2][d] + red[3][d];
}

// ---------------------------------------------------------------------------
// Kernel 1b: bf16 GEMM 128x128, gld16 both operands, swizzled (round-14).
// ---------------------------------------------------------------------------
template <typename CT>
__global__ __launch_bounds__(256) void gemm_bf(const unsigned short* __restrict__ A,
                                               const unsigned short* __restrict__ Wt,
                                               CT* __restrict__ C,
                                               const float* __restrict__ bias,
                                               const unsigned short* __restrict__ res,
                                               int relu) {
    __shared__ __align__(16) unsigned short As[128][32];
    __shared__ __align__(16) unsigned short Ws[128][32];

    const int t = threadIdx.x;
    const int m0 = blockIdx.x * 128;
    const int n0 = blockIdx.y * 128;
    const int w = t >> 6, lane = t & 63;
    const int quad = lane >> 4, l16 = lane & 15;
    const int wm = w & 1, wn = w >> 1;
    const int srow = 16 * w + (lane >> 2);
    const int scol = 8 * ((lane & 3) ^ ((lane >> 3) & 3));
    const int swr = (quad ^ ((l16 >> 1) & 3)) * 8;

    f32x4 acc[4][4];
#pragma unroll
    for (int i = 0; i < 4; ++i)
#pragma unroll
        for (int j = 0; j < 4; ++j) acc[i][j] = (f32x4){0.f, 0.f, 0.f, 0.f};

    for (int k0 = 0; k0 < DM; k0 += 32) {
#pragma unroll
        for (int j = 0; j < 2; ++j) {
            gld16(&A[(size_t)(m0 + srow + 64 * j) * DM + k0 + scol],
                  &As[16 * w + 64 * j][0]);
            gld16(&Wt[(size_t)(n0 + srow + 64 * j) * DM + k0 + scol],
                  &Ws[16 * w + 64 * j][0]);
        }
        __syncthreads();

        bf16x8 av[4], bv[4];
#pragma unroll
        for (int i = 0; i < 4; ++i)
            av[i] = *(const bf16x8*)&As[wm * 64 + 16 * i + l16][swr];
#pragma unroll
        for (int i = 0; i < 4; ++i)
            bv[i] = *(const bf16x8*)&Ws[wn * 64 + 16 * i + l16][swr];
#pragma unroll
        for (int i = 0; i < 4; ++i)
#pragma unroll
            for (int j = 0; j < 4; ++j)
                acc[i][j] = __builtin_amdgcn_mfma_f32_16x16x32_bf16(av[i], bv[j], acc[i][j], 0, 0, 0);
        __syncthreads();
    }

#pragma unroll
    for (int i = 0; i < 4; ++i)
#pragma unroll
        for (int j = 0; j < 4; ++j) {
            const int gn = n0 + wn * 64 + 16 * j + l16;
            const float badd = bias ? bias[gn] : 0.0f;
#pragma unroll
            for (int r = 0; r < 4; ++r) {
                const int gm = m0 + wm * 64 + 16 * i + quad * 4 + r;
                float cv = acc[i][j][r] + badd;
                if (relu) cv = fmaxf(cv, 0.0f);
                if (res) cv += b2f(res[(size_t)gm * DM + gn]);
                if constexpr (std::is_same<CT, float>::value) {
                    C[(size_t)gm * DM + gn] = cv;
                } else {
                    C[(size_t)gm * DM + gn] = f2b(cv);
                }
            }
        }
}

// ---------------------------------------------------------------------------
// Kernel 1c: merged mha + ffn-hidden GEMM, swizzled (round-14).
// ---------------------------------------------------------------------------
__global__ __launch_bounds__(256) void gemm_mh(const unsigned short* __restrict__ A,
                                               const unsigned short* __restrict__ wt,
                                               unsigned short* __restrict__ cm,
                                               unsigned short* __restrict__ ch,
                                               const float* __restrict__ d1b) {
    __shared__ __align__(16) unsigned short As[128][32];
    __shared__ __align__(16) unsigned short Ws[128][32];

    const int t = threadIdx.x;
    const int unit = blockIdx.y / 6;
    const unsigned short* Wt = wt + (size_t)(unit ? 6 : 3) * DM * DM;
    unsigned short* C = unit ? ch : cm;
    const int m0 = blockIdx.x * 128;
    const int n0 = (blockIdx.y % 6) * 128;
    const int w = t >> 6, lane = t & 63;
    const int quad = lane >> 4, l16 = lane & 15;
    const int wm = w & 1, wn = w >> 1;
    const int srow = 16 * w + (lane >> 2);
    const int scol = 8 * ((lane & 3) ^ ((lane >> 3) & 3));
    const int swr = (quad ^ ((l16 >> 1) & 3)) * 8;

    f32x4 acc[4][4];
#pragma unroll
    for (int i = 0; i < 4; ++i)
#pragma unroll
        for (int j = 0; j < 4; ++j) acc[i][j] = (f32x4){0.f, 0.f, 0.f, 0.f};

    for (int k0 = 0; k0 < DM; k0 += 32) {
#pragma unroll
        for (int j = 0; j < 2; ++j) {
            gld16(&A[(size_t)(m0 + srow + 64 * j) * DM + k0 + scol],
                  &As[16 * w + 64 * j][0]);
            gld16(&Wt[(size_t)(n0 + srow + 64 * j) * DM + k0 + scol],
                  &Ws[16 * w + 64 * j][0]);
        }
        __syncthreads();

        bf16x8 av[4], bv[4];
#pragma unroll
        for (int i = 0; i < 4; ++i)
            av[i] = *(const bf16x8*)&As[wm * 64 + 16 * i + l16][swr];
#pragma unroll
        for (int i = 0; i < 4; ++i)
            bv[i] = *(const bf16x8*)&Ws[wn * 64 + 16 * i + l16][swr];
#pragma unroll
        for (int i = 0; i < 4; ++i)
#pragma unroll
            for (int j = 0; j < 4; ++j)
                acc[i][j] = __builtin_amdgcn_mfma_f32_16x16x32_bf16(av[i], bv[j], acc[i][j], 0, 0, 0);
        __syncthreads();
    }

#pragma unroll
    for (int i = 0; i < 4; ++i)
#pragma unroll
        for (int j = 0; j < 4; ++j) {
            const int gn = n0 + wn * 64 + 16 * j + l16;
            const float badd = unit ? d1b[gn] : 0.0f;
#pragma unroll
            for (int r = 0; r < 4; ++r) {
                const int gm = m0 + wm * 64 + 16 * i + quad * 4 + r;
                float cv = acc[i][j][r] + badd;
                if (unit) cv = fmaxf(cv, 0.0f);
                C[(size_t)gm * DM + gn] = f2b(cv);
            }
        }
}

// ---------------------------------------------------------------------------
// Kernel 2: MFMA flash attention + mask-aware skipping (round-13, passing).
// ---------------------------------------------------------------------------
__global__ __launch_bounds__(256) void attn_mfma(const unsigned short* Q,
                                                 const unsigned short* __restrict__ K,
                                                 const unsigned short* __restrict__ V,
                                                 unsigned short* O,
                                                 const int* __restrict__ lens,
                                                 const float* __restrict__ vp) {
    __shared__ __align__(16) unsigned short Ks[64][72];
    __shared__ __align__(16) unsigned short Vt[64][72];
    __shared__ __align__(16) unsigned short Ps[4][16][72];

    const int t = threadIdx.x;
    const int bid = blockIdx.x;
    const int q0 = (bid & 15) * 64;
    const int h = (bid >> 4) % NH;
    const int b = bid / (16 * NH);
    const int vl1 = lens[b];
    const int vl2 = lens[8 + b];
    const int wid = t >> 6;
    const int lane = t & 63;
    const int quad = lane >> 4;
    const int l16 = lane & 15;
    const size_t vpb = (size_t)(b * NH + h) * 8 * 64;

    if (q0 >= vl2 || vl1 == 0) {
        float vm[4];
#pragma unroll
        for (int ct = 0; ct < 4; ++ct) {
            float s = 0.0f;
#pragma unroll
            for (int c = 0; c < 8; ++c) s += vp[vpb + (size_t)c * 64 + 16 * ct + l16];
            vm[ct] = s * (1.0f / 1024.0f);
        }
#pragma unroll
        for (int r = 0; r < 4; ++r) {
            const size_t row = (size_t)(b * SEQ + q0 + 16 * wid + quad * 4 + r);
#pragma unroll
            for (int ct = 0; ct < 4; ++ct)
                O[row * DM + h * HD + 16 * ct + l16] = f2b(vm[ct]);
        }
        return;
    }

    bf16x8 qa0, qa1;
    {
        const unsigned short* qp =
            &Q[(size_t)(b * SEQ + q0 + 16 * wid + l16) * DM + h * HD + quad * 8];
        qa0 = *(const bf16x8*)qp;
        qa1 = *(const bf16x8*)(qp + 32);
    }

    f32x4 o[4];
#pragma unroll
    for (int ct = 0; ct < 4; ++ct) o[ct] = (f32x4){0.f, 0.f, 0.f, 0.f};
    float suml[4];
    bool rbad[4];
#pragma unroll
    for (int r = 0; r < 4; ++r) {
        suml[r] = 0.0f;
        rbad[r] = (q0 + 16 * wid + quad * 4 + r) >= vl2;
    }

    const int nt = (vl1 + 63) >> 6;

    const int kkr = t >> 3;
    const int khc = (t & 7) * 8;
    const unsigned short* kbase = &K[(size_t)(b * SEQ) * DM + h * HD];
    const unsigned short* vbase = &V[(size_t)(b * SEQ) * DM + h * HD];

    uint4 kr0 = *(const uint4*)&kbase[(size_t)kkr * DM + khc];
    uint4 kr1 = *(const uint4*)&kbase[(size_t)(kkr + 32) * DM + khc];
    uint4 vr0 = *(const uint4*)&vbase[(size_t)lane * DM + wid * 16];
    uint4 vr1 = *(const uint4*)&vbase[(size_t)lane * DM + wid * 16 + 8];

    const int k2 = l16 >> 2;

    for (int tile = 0; tile < nt; ++tile) {
        const int c0 = tile * 64;
        *(uint4*)&Ks[kkr][khc] = kr0;
        *(uint4*)&Ks[kkr + 32][khc] = kr1;
        {
            union { uint4 u; unsigned short s[8]; } va, vb;
            va.u = vr0; vb.u = vr1;
#pragma unroll
            for (int j = 0; j < 8; ++j) Vt[wid * 16 + j][lane] = va.s[j];
#pragma unroll
            for (int j = 0; j < 8; ++j) Vt[wid * 16 + 8 + j][lane] = vb.s[j];
        }
        __syncthreads();

        if (tile < nt - 1) {
            const int c1 = c0 + 64;
            kr0 = *(const uint4*)&kbase[(size_t)(c1 + kkr) * DM + khc];
            kr1 = *(const uint4*)&kbase[(size_t)(c1 + kkr + 32) * DM + khc];
            vr0 = *(const uint4*)&vbase[(size_t)(c1 + lane) * DM + wid * 16];
            vr1 = *(const uint4*)&vbase[(size_t)(c1 + lane) * DM + wid * 16 + 8];
        }

        f32x4 s[4];
#pragma unroll
        for (int ct = 0; ct < 4; ++ct) {
            f32x4 acc = (f32x4){0.f, 0.f, 0.f, 0.f};
            bf16x8 b0v = *(const bf16x8*)&Ks[16 * ct + l16][quad * 8];
            bf16x8 b1v = *(const bf16x8*)&Ks[16 * ct + l16][32 + quad * 8];
            acc = __builtin_amdgcn_mfma_f32_16x16x32_bf16(qa0, b0v, acc, 0, 0, 0);
            acc = __builtin_amdgcn_mfma_f32_16x16x32_bf16(qa1, b1v, acc, 0, 0, 0);
            s[ct] = acc;
        }
#pragma unroll
        for (int ct = 0; ct < 4; ++ct) {
            const bool kok = (c0 + 16 * ct + l16) < vl1;
#pragma unroll
            for (int r = 0; r < 4; ++r) {
                float e = __builtin_amdgcn_exp2f(s[ct][r]);
                float p = kok ? e : 0.0f;
                s[ct][r] = p;
                suml[r] += p;
            }
        }
#pragma unroll
        for (int ct = 0; ct < 4; ++ct) {
            const int gidx = 2 * ct + (l16 >> 3);
            const int c = l16 & 7;
            const int gs = (gidx ^ quad) * 8 + c;
#pragma unroll
            for (int r = 0; r < 4; ++r)
                Ps[wid][quad * 4 + r][gs] = f2b(s[ct][r]);
        }
        bf16x8 pa0 = *(const bf16x8*)&Ps[wid][l16][(quad ^ k2) * 8];
        bf16x8 pa1 = *(const bf16x8*)&Ps[wid][l16][((4 + quad) ^ k2) * 8];
#pragma unroll
        for (int ct = 0; ct < 4; ++ct) {
            bf16x8 vb0 = *(const bf16x8*)&Vt[16 * ct + l16][quad * 8];
            bf16x8 vb1 = *(const bf16x8*)&Vt[16 * ct + l16][32 + quad * 8];
            o[ct] = __builtin_amdgcn_mfma_f32_16x16x32_bf16(pa0, vb0, o[ct], 0, 0, 0);
            o[ct] = __builtin_amdgcn_mfma_f32_16x16x32_bf16(pa1, vb1, o[ct], 0, 0, 0);
        }
        __syncthreads();
    }

#pragma unroll
    for (int d = 1; d < 16; d <<= 1) {
#pragma unroll
        for (int r = 0; r < 4; ++r) suml[r] += __shfl_xor(suml[r], d, 64);
    }

    float vm[4];
    if (rbad[0] || rbad[3]) {
#pragma unroll
        for (int ct = 0; ct < 4; ++ct) {
            float s = 0.0f;
#pragma unroll
            for (int c = 0; c < 8; ++c) s += vp[vpb + (size_t)c * 64 + 16 * ct + l16];
            vm[ct] = s * (1.0f / 1024.0f);
        }
    }
#pragma unroll
    for (int r = 0; r < 4; ++r) {
        const float inv = 1.0f / suml[r];
        const size_t row = (size_t)(b * SEQ + q0 + 16 * wid + quad * 4 + r);
#pragma unroll
        for (int ct = 0; ct < 4; ++ct) {
            const float val = rbad[r] ? vm[ct] : o[ct][r] * inv;
            O[row * DM + h * HD + 16 * ct + l16] = f2b(val);
        }
    }
}

// ---------------------------------------------------------------------------
// Kernel 3: row LayerNorm over D=768, fp32 in/out, IN PLACE on d_out.
// ---------------------------------------------------------------------------
__global__ __launch_bounds__(256) void ln_kernel(float* __restrict__ X,
                                                 const float* __restrict__ g,
                                                 const float* __restrict__ bvec) {
    __shared__ float red[256];
    const int row = blockIdx.x;
    const int t = threadIdx.x;
    float* xr = X + (size_t)row * DM;
    float x0 = xr[t];
    float x1 = xr[t + 256];
    float x2 = xr[t + 512];
    red[t] = x0 + x1 + x2;
    __syncthreads();
    for (int off = 128; off > 0; off >>= 1) {
        if (t < off) red[t] += red[t + off];
        __syncthreads();
    }
    float mu = red[0] * (1.0f / 768.0f);
    __syncthreads();
    float d0 = x0 - mu, d1 = x1 - mu, d2 = x2 - mu;
    red[t] = d0 * d0 + d1 * d1 + d2 * d2;
    __syncthreads();
    for (int off = 128; off > 0; off >>= 1) {
        if (t < off) red[t] += red[t + off];
        __syncthreads();
    }
    float rstd = rsqrtf(red[0] * (1.0f / 768.0f) + 1e-5f);
    xr[t]       = d0 * rstd * g[t]       + bvec[t];
    xr[t + 256] = d1 * rstd * g[t + 256] + bvec[t + 256];
    xr[t + 512] = d2 * rstd * g[t + 512] + bvec[t + 512];
}

// ---------------------------------------------------------------------------
extern "C" void kernel_launch(void* const* d_in, const int* in_sizes, int n_in,
                              void* d_out, int out_size, void* d_ws, size_t ws_size,
                              hipStream_t stream) {
    const float* queries = (const float*)d_in[0];
    const float* keys    = (const float*)d_in[1];
    const float* values  = (const float*)d_in[2];
    const int* mask1 = (const int*)d_in[3];
    const int* mask2 = (const int*)d_in[4];
    const float* Wq  = (const float*)d_in[5];
    const float* Wk  = (const float*)d_in[6];
    const float* Wv  = (const float*)d_in[7];
    const float* Wo  = (const float*)d_in[8];
    const float* d1w = (const float*)d_in[9];
    const float* d1b = (const float*)d_in[10];
    const float* d2w = (const float*)d_in[11];
    const float* d2b = (const float*)d_in[12];
    const float* lng = (const float*)d_in[13];
    const float* lnb = (const float*)d_in[14];

    // workspace: [lens 256B][vp 192KB][b0][b1][b2][Wt x7][aq][ak][av]  (~84 MB)
    char* ws = (char*)d_ws;
    int* lens = (int*)ws;
    float* vp = (float*)(ws + 256);                                  // 96*8*64 fp32
    const size_t VP = (size_t)96 * 8 * 64 * sizeof(float);
    const size_t NB = (size_t)NROWS * DM * sizeof(unsigned short);   // 12.58 MB
    const size_t WT = (size_t)DM * DM;
    unsigned short* b0 = (unsigned short*)(ws + 256 + VP);
    unsigned short* b1 = (unsigned short*)(ws + 256 + VP + NB);
    unsigned short* b2 = (unsigned short*)(ws + 256 + VP + 2 * NB);
    unsigned short* wt = (unsigned short*)(ws + 256 + VP + 3 * NB);  // 7 x 768*768
    unsigned short* aq = (unsigned short*)(ws + 256 + VP + 3 * NB + 7 * WT * sizeof(unsigned short));
    unsigned short* ak = aq + (size_t)NROWS * DM;
    unsigned short* av = ak + (size_t)NROWS * DM;
    float* xout = (float*)d_out;

    // merged prep: weight cvt (z<6), wod1 + lens (z==6), input cvt (z>=7)
    prep_kernel<<<dim3(24, 24, 23), 256, 0, stream>>>(Wq, Wk, Wv, Wo, d1w, d2w,
                                                      wt, mask1, mask2, lens,
                                                      queries, keys, values,
                                                      aq, ak, av);

    // grouped QKV projection (Q output pre-scaled for exp2 softmax)
    qkv_gemm<<<dim3(64, 18), 256, 0, stream>>>(aq, ak, av, wt, b0, b1, b2);

    // per-(b,h) V column partial sums for the uniform-softmax mean path
    vpart_kernel<<<dim3(96, 8), 256, 0, stream>>>(b2, vp);

    attn_mfma<<<16 * NH * BATCH, 256, 0, stream>>>(b0, b1, b2, b0, lens, vp);  // O over Q

    // merged: mha -> b1, h = relu(attnout@Wod1 + d1b) -> b2
    gemm_mh<<<dim3(64, 12), 256, 0, stream>>>(b0, wt, b1, b2, d1b);

    // x = h @ d2w + d2b + mha -> d_out (fp32)
    gemm_bf<float><<<dim3(64, 6), 256, 0, stream>>>(b2, wt + 5 * WT, xout, d2b, b1, 0);

    ln_kernel<<<NROWS, 256, 0, stream>>>(xout, lng, lnb);  // in place
}